// Round 12
// baseline (295.256 us; speedup 1.0000x reference)
//
#include <hip/hip_runtime.h>
#include <cstdint>

#define NEGF (-1e18f)
#define GK 2048   // GEMM K
#define GN 1024   // GEMM N

typedef __attribute__((ext_vector_type(8))) short short8;     // 8 bf16 (4 VGPRs) MFMA A/B frag
typedef __attribute__((ext_vector_type(4))) float f32x4;      // MFMA C/D frag
typedef __attribute__((ext_vector_type(4))) unsigned short us4;
typedef __attribute__((ext_vector_type(8))) unsigned short us8;

__device__ __forceinline__ unsigned short f2bf(float f) {
    unsigned int u = __float_as_uint(f);
    u += 0x7FFFu + ((u >> 16) & 1u);          // RNE
    return (unsigned short)(u >> 16);
}
__device__ __forceinline__ float bf2f(unsigned short h) {
    return __uint_as_float(((unsigned int)h) << 16);
}
__device__ __forceinline__ float gelu_erf(float x) {
    return 0.5f * x * (1.0f + erff(x * 0.70710678118654752f));
}
// tanh-form GELU: max |diff| vs erf-GELU < 1e-3 (small vs 2.1e-2 threshold)
__device__ __forceinline__ float gelu_fast(float x) {
    const float y = 1.5957691216057308f * (x + 0.044715f * x * x * x);
    const float t = 1.0f - 2.0f / (__expf(y) + 1.0f);
    return 0.5f * x * (1.0f + t);
}
__device__ __forceinline__ void async_copy16(const void* g, void* l) {
    __builtin_amdgcn_global_load_lds(
        (const __attribute__((address_space(1))) unsigned int*)g,
        (__attribute__((address_space(3))) unsigned int*)l,
        16, 0, 0);
}

// ---------------- 1. weight transpose + bf16 convert (both weights in one dispatch)
__global__ __launch_bounds__(256) void wtrans2_kernel(const float* __restrict__ wmot,
                                                      const float* __restrict__ wapp,
                                                      unsigned short* __restrict__ wmotT,
                                                      unsigned short* __restrict__ wappT) {
    const int which = blockIdx.x >> 10;
    const float* w = which ? wapp : wmot;
    unsigned short* wT = which ? wappT : wmotT;
    const int idx = (blockIdx.x & 1023) * 256 + threadIdx.x;
    const int n = idx & 1023;
    const int k0 = (idx >> 10) << 3;
    us8 o;
    #pragma unroll
    for (int j = 0; j < 8; ++j) o[j] = f2bf(w[(size_t)(k0 + j) * 1024 + n]);
    *(us8*)(wT + (size_t)n * 2048 + k0) = o;
}

// ---------------- 2. fused: motion score + window softmax + app/vid bf16 convert
__global__ __launch_bounds__(256) void prep2_kernel(const float* __restrict__ clip_ft,
                                                    const int* __restrict__ lens,
                                                    const float* __restrict__ w_mot_wei,
                                                    const float* __restrict__ bsc,
                                                    unsigned short* __restrict__ app,   // [B][256][2048]
                                                    unsigned short* __restrict__ vid) { // [B][256][2048]
    __shared__ float sm2[2][4];
    const int b = blockIdx.x >> 3;
    const int c = blockIdx.x & 7;
    const int t = threadIdx.x;
    const int lane = t & 63, wv = t >> 6;
    const int d0 = t * 8;
    const int l0 = c * 32;
    const int len = lens[b];
    const float bias = bsc[0];
    const float* base = clip_ft + ((size_t)b * 256) * 2048 + d0;
    float wm[8];
    {
        f32x4 u = *(const f32x4*)(w_mot_wei + d0);
        f32x4 v = *(const f32x4*)(w_mot_wei + d0 + 4);
        #pragma unroll
        for (int j = 0; j < 4; ++j) { wm[j] = u[j]; wm[4 + j] = v[j]; }
    }
    float x0[8], x1[8], cur[8];
    float sc0 = NEGF, sc1 = NEGF, sc2 = NEGF;
    for (int i = 0; i < 34; ++i) {
        const int l = l0 + i;
        if (l < 256) {
            const f32x4* p = (const f32x4*)(base + (size_t)l * 2048);
            f32x4 u = p[0], v = p[1];
            #pragma unroll
            for (int j = 0; j < 4; ++j) { cur[j] = u[j]; cur[4 + j] = v[j]; }
            if (i < 32) {
                us8 o;
                #pragma unroll
                for (int j = 0; j < 8; ++j) o[j] = f2bf(cur[j]);
                *(us8*)(app + ((size_t)b * 256 + l) * 2048 + d0) = o;
            }
            float p8 = cur[0]*wm[0] + cur[1]*wm[1] + cur[2]*wm[2] + cur[3]*wm[3]
                     + cur[4]*wm[4] + cur[5]*wm[5] + cur[6]*wm[6] + cur[7]*wm[7];
            #pragma unroll
            for (int off = 32; off; off >>= 1) p8 += __shfl_xor(p8, off);
            if (lane == 0) sm2[i & 1][wv] = p8;
        }
        __syncthreads();                           // uniform; publishes sm2[i&1]
        if (l < 256) {
            float s = (sm2[i & 1][0] + sm2[i & 1][1]) + (sm2[i & 1][2] + sm2[i & 1][3]) + bias;
            sc2 = (l >= len) ? NEGF : s;
        }
        if (i >= 2) {
            const int lw = l - 2;
            if (lw < 254) {
                const float mx = fmaxf(sc0, fmaxf(sc1, sc2));
                const float e0 = expf(sc0 - mx), e1 = expf(sc1 - mx), e2 = expf(sc2 - mx);
                const float inv = 1.0f / (e0 + e1 + e2);
                const float a0 = e0 * inv, a1 = e1 * inv, a2 = e2 * inv;
                us8 o;
                #pragma unroll
                for (int j = 0; j < 8; ++j) o[j] = f2bf(a0 * x0[j] + a1 * x1[j] + a2 * cur[j]);
                *(us8*)(vid + ((size_t)b * 256 + lw) * 2048 + d0) = o;
            } else if (lw < 256) {
                us8 z = {};                         // zero pad rows 254,255
                *(us8*)(vid + ((size_t)b * 256 + lw) * 2048 + d0) = z;
            }
        }
        #pragma unroll
        for (int j = 0; j < 8; ++j) { x0[j] = x1[j]; x1[j] = cur[j]; }
        sc0 = sc1; sc1 = sc2;
    }
}

// ---------------- 3. fused dual bf16 MFMA GEMM — 128x256 tile, BK=32, 8 waves (2Mx4N,
// 64x64 per wave), 3 LDS bufs (72KB) depth-2 counted-vmcnt pipeline (R6-proven),
// __launch_bounds__(512,4): 4 waves/SIMD, 2 blocks/CU -> cross-block TLP hides the
// barrier-delimited read<->MFMA serialization that pinned the 1-block/CU 8-phase at 29%.
// 0-conflict XOR swizzle slot^=(row>>1)&3 both-sides; bijective XCD swizzle (1024%8==0).
__global__ __launch_bounds__(512, 4) void gemm3q_kernel(
        const unsigned short* __restrict__ Avid, const unsigned short* __restrict__ Aapp,
        const unsigned short* __restrict__ Bmot, const unsigned short* __restrict__ Bapp,
        const float* __restrict__ bmot, const float* __restrict__ bapp,
        const float* __restrict__ w_pool,
        unsigned short* __restrict__ Cmot, unsigned short* __restrict__ Capp,
        float* __restrict__ pspart) {             // [2][16384][16] strip partials
    __shared__ __align__(16) unsigned short lds_[3 * 12288]; // 72KB: 3 x (A 8KB | B 16KB)
    const int bid = blockIdx.x;
    const int virt = (bid & 7) * 128 + (bid >> 3);            // XCD-bijective
    const int which = virt >> 9;
    const int rem = virt & 511;
    const int mtile = rem >> 2, ntile = rem & 3;  // ntile fastest: B L2-resident per XCD
    const unsigned short* A  = which ? Aapp : Avid;
    const unsigned short* Bt = which ? Bapp : Bmot;
    const float* bias        = which ? bapp : bmot;
    unsigned short* C        = which ? Capp : Cmot;
    const int row0 = mtile * 128, col0 = ntile * 256;
    const int t = threadIdx.x, lane = t & 63, wave = t >> 6;
    const int wm = wave >> 2, wn = wave & 3;      // 2M x 4N waves, 64x64 each
    const int lr = lane & 15, sl = lane >> 4;     // frag row-in-16, k-slot 0..3

    // staging: thread t -> LDS[srow][t&3] linear; source k-slot pre-swizzled:
    // involution slot ^= (row>>1)&3 (R6-proven, conflicts=0)
    const int srow = t >> 2;                      // 0..127
    const int sk16 = (t & 3) ^ ((srow >> 1) & 3);
    const unsigned short* gA  = A  + (size_t)(row0 + srow) * GK + sk16 * 8;
    const unsigned short* gB0 = Bt + (size_t)(col0 + srow) * GK + sk16 * 8;        // cols 0-127
    const unsigned short* gB1 = Bt + (size_t)(col0 + srow + 128) * GK + sk16 * 8;  // cols 128-255
    const int wbase = wave << 9;                  // 1KB per wave within a call

#define STAGE(d, kt) do { \
    async_copy16(gA  + (kt) * 32, lds_ + (d) * 12288 +        wbase); \
    async_copy16(gB0 + (kt) * 32, lds_ + (d) * 12288 + 4096 + wbase); \
    async_copy16(gB1 + (kt) * 32, lds_ + (d) * 12288 + 8192 + wbase); } while (0)

#define KSTEP(CUR) do { \
    const unsigned short* lb = lds_ + (CUR) * 12288; \
    short8 aF[4], bF[4]; \
    _Pragma("unroll") \
    for (int m = 0; m < 4; ++m) { \
        const int r = wm * 64 + m * 16 + lr; \
        aF[m] = *(const short8*)(lb + r * 32 + ((sl ^ ((r >> 1) & 3)) << 3)); \
    } \
    _Pragma("unroll") \
    for (int n = 0; n < 4; ++n) { \
        const int cc = wn * 64 + n * 16 + lr; \
        bF[n] = *(const short8*)(lb + 4096 + cc * 32 + ((sl ^ ((cc >> 1) & 3)) << 3)); \
    } \
    _Pragma("unroll") \
    for (int m = 0; m < 4; ++m) \
        _Pragma("unroll") \
        for (int n = 0; n < 4; ++n) \
            acc[m][n] = __builtin_amdgcn_mfma_f32_16x16x32_bf16(aF[m], bF[n], acc[m][n], 0, 0, 0); \
    } while (0)

    f32x4 acc[4][4] = {};
    STAGE(0, 0);
    STAGE(1, 1);

    int cur = 0, stg = 2;
    #pragma unroll 3
    for (int kt = 0; kt < 62; ++kt) {
        // stage(kt) retired; stage(kt+1)'s 3 calls stay in flight
        asm volatile("s_waitcnt vmcnt(3)" ::: "memory");
        __builtin_amdgcn_s_barrier();
        __builtin_amdgcn_sched_barrier(0);
        STAGE(stg, kt + 2);                        // full compute phase of flight time
        KSTEP(cur);
        cur = (cur == 2) ? 0 : cur + 1;
        stg = (stg == 2) ? 0 : stg + 1;
    }
    // kt = 62: outstanding = stage(62) 3 + stage(63) 3
    asm volatile("s_waitcnt vmcnt(3)" ::: "memory");
    __builtin_amdgcn_s_barrier();
    __builtin_amdgcn_sched_barrier(0);
    KSTEP(cur);
    cur = (cur == 2) ? 0 : cur + 1;
    // kt = 63: drain
    asm volatile("s_waitcnt vmcnt(0)" ::: "memory");
    __builtin_amdgcn_s_barrier();
    __builtin_amdgcn_sched_barrier(0);
    KSTEP(cur);
#undef STAGE
#undef KSTEP

    // epilogue: C/D layout col=lane&15, row=(lane>>4)*4+i (HW-verified m89/m91)
    // + pool-dot partials per 64-col strip (strip = ntile*4 + wn), shfl-reduced over lr group
    float wp[4], bz[4];
    #pragma unroll
    for (int n = 0; n < 4; ++n) {
        const int col = col0 + wn * 64 + n * 16 + lr;
        wp[n] = w_pool[col];
        bz[n] = bias[col];
    }
    const int strip = ntile * 4 + wn;
    #pragma unroll
    for (int m = 0; m < 4; ++m) {
        #pragma unroll
        for (int i = 0; i < 4; ++i) {
            const int row = row0 + wm * 64 + m * 16 + sl * 4 + i;
            float pr = 0.f;
            #pragma unroll
            for (int n = 0; n < 4; ++n) {
                const int col = col0 + wn * 64 + n * 16 + lr;
                const float g = gelu_fast(acc[m][n][i] + bz[n]);
                pr += g * wp[n];
                C[(size_t)row * GN + col] = f2bf(g);
            }
            #pragma unroll
            for (int off = 8; off; off >>= 1) pr += __shfl_xor(pr, off);  // reduce over lr group
            if (lr == 0) pspart[((size_t)which * 16384 + row) * 16 + strip] = pr;
        }
    }
}

// ---------------- 4. masked softmax + weighted sum; block = (b, which); thread owns 4 cols
__global__ __launch_bounds__(256) void pool2_kernel(const unsigned short* __restrict__ motion,
                                                    const unsigned short* __restrict__ appearance,
                                                    const float* __restrict__ pspart,
                                                    const int* __restrict__ lens,
                                                    const float* __restrict__ b_pool,
                                                    float* __restrict__ out) {
    __shared__ float sm[256];
    __shared__ float red[8];
    const int which = blockIdx.x & 1;
    const int b = blockIdx.x >> 1;
    const unsigned short* mat = (which ? appearance : motion) + (size_t)b * 256 * 1024;
    const int Lm = which ? 256 : 254;
    const int valid = which ? lens[b] : lens[b] - 2;
    const int t = threadIdx.x, lane = t & 63, wv = t >> 6;
    float v = NEGF;
    if (t < valid) {
        const float* pp = pspart + ((size_t)which * 16384 + b * 256 + t) * 16;
        float s = 0.f;
        #pragma unroll
        for (int j = 0; j < 16; ++j) s += pp[j];
        v = gelu_erf(s + b_pool[0]);
    }
    float mx = v;
    #pragma unroll
    for (int off = 32; off; off >>= 1) mx = fmaxf(mx, __shfl_xor(mx, off));
    if (lane == 0) red[wv] = mx;
    __syncthreads();
    mx = fmaxf(fmaxf(red[0], red[1]), fmaxf(red[2], red[3]));
    const float e = expf(v - mx);                 // masked rows -> exactly 0
    float s = e;
    #pragma unroll
    for (int off = 32; off; off >>= 1) s += __shfl_xor(s, off);
    if (lane == 0) red[4 + wv] = s;
    __syncthreads();
    s = red[4] + red[5] + red[6] + red[7];
    sm[t] = e / s;
    __syncthreads();
    const int col0 = t * 4;
    float a0 = 0.f, a1 = 0.f, a2 = 0.f, a3 = 0.f;
    for (int l = 0; l < Lm; ++l) {
        const float al = sm[l];                   // uniform scalar -> cheap branch
        if (al > 0.f) {
            us4 hv = *(const us4*)(mat + (size_t)l * 1024 + col0);
            a0 += al * bf2f(hv[0]);
            a1 += al * bf2f(hv[1]);
            a2 += al * bf2f(hv[2]);
            a3 += al * bf2f(hv[3]);
        }
    }
    float* o = out + (size_t)b * 2048 + which * 1024 + col0;
    o[0] = a0; o[1] = a1; o[2] = a2; o[3] = a3;
}

extern "C" void kernel_launch(void* const* d_in, const int* in_sizes, int n_in,
                              void* d_out, int out_size, void* d_ws, size_t ws_size,
                              hipStream_t stream) {
    const float* clip_ft   = (const float*)d_in[0];
    const int*   clip_lens = (const int*)d_in[1];
    const float* w_mot_wei = (const float*)d_in[2];
    const float* b_mot_wei = (const float*)d_in[3];
    const float* w_mot_fc  = (const float*)d_in[4];
    const float* b_mot_fc  = (const float*)d_in[5];
    const float* w_app_fc  = (const float*)d_in[6];
    const float* b_app_fc  = (const float*)d_in[7];
    const float* w_pool    = (const float*)d_in[8];
    const float* b_pool    = (const float*)d_in[9];
    float* out = (float*)d_out;

    char* ws = (char*)d_ws;
    size_t off = 0;
    auto carve = [&](size_t bytes) { void* p = ws + off; off += (bytes + 255) & ~(size_t)255; return p; };
    float*          pspart = (float*)carve((size_t)2 * 16384 * 16 * 4);
    unsigned short* wmotT  = (unsigned short*)carve((size_t)1024 * 2048 * 2);
    unsigned short* wappT  = (unsigned short*)carve((size_t)1024 * 2048 * 2);
    unsigned short* appb   = (unsigned short*)carve((size_t)64 * 256 * 2048 * 2);
    unsigned short* vidb   = (unsigned short*)carve((size_t)64 * 256 * 2048 * 2);  // padded rows
    unsigned short* motion = (unsigned short*)carve((size_t)64 * 256 * 1024 * 2);  // padded rows
    unsigned short* appear = (unsigned short*)carve((size_t)64 * 256 * 1024 * 2);
    (void)ws_size; (void)in_sizes; (void)n_in; (void)out_size;

    wtrans2_kernel<<<2048, 256, 0, stream>>>(w_mot_fc, w_app_fc, wmotT, wappT);
    prep2_kernel<<<512, 256, 0, stream>>>(clip_ft, clip_lens, w_mot_wei, b_mot_wei, appb, vidb);
    gemm3q_kernel<<<1024, 512, 0, stream>>>(vidb, appb, wmotT, wappT,
                                            b_mot_fc, b_app_fc, w_pool, motion, appear, pspart);
    pool2_kernel<<<128, 256, 0, stream>>>(motion, appear, pspart, clip_lens, b_pool, out);
}

// Round 13
// 218.316 us; speedup vs baseline: 1.3524x; 1.3524x over previous
//
#include <hip/hip_runtime.h>
#include <cstdint>

#define NEGF (-1e18f)
#define GK 2048   // GEMM K
#define GN 1024   // GEMM N

typedef __attribute__((ext_vector_type(8))) short short8;     // 8 bf16 (4 VGPRs) MFMA A/B frag
typedef __attribute__((ext_vector_type(4))) float f32x4;      // MFMA C/D frag
typedef __attribute__((ext_vector_type(4))) unsigned short us4;
typedef __attribute__((ext_vector_type(8))) unsigned short us8;

__device__ __forceinline__ unsigned short f2bf(float f) {
    unsigned int u = __float_as_uint(f);
    u += 0x7FFFu + ((u >> 16) & 1u);          // RNE
    return (unsigned short)(u >> 16);
}
__device__ __forceinline__ float bf2f(unsigned short h) {
    return __uint_as_float(((unsigned int)h) << 16);
}
__device__ __forceinline__ float gelu_erf(float x) {
    return 0.5f * x * (1.0f + erff(x * 0.70710678118654752f));
}
// tanh-form GELU: max |diff| vs erf-GELU < 1e-3 (small vs 2.1e-2 threshold)
__device__ __forceinline__ float gelu_fast(float x) {
    const float y = 1.5957691216057308f * (x + 0.044715f * x * x * x);
    const float t = 1.0f - 2.0f / (__expf(y) + 1.0f);
    return 0.5f * x * (1.0f + t);
}
__device__ __forceinline__ void async_copy16(const void* g, void* l) {
    __builtin_amdgcn_global_load_lds(
        (const __attribute__((address_space(1))) unsigned int*)g,
        (__attribute__((address_space(3))) unsigned int*)l,
        16, 0, 0);
}

// ---------------- 1. weight transpose + bf16 convert (both weights in one dispatch)
__global__ __launch_bounds__(256) void wtrans2_kernel(const float* __restrict__ wmot,
                                                      const float* __restrict__ wapp,
                                                      unsigned short* __restrict__ wmotT,
                                                      unsigned short* __restrict__ wappT) {
    const int which = blockIdx.x >> 10;
    const float* w = which ? wapp : wmot;
    unsigned short* wT = which ? wappT : wmotT;
    const int idx = (blockIdx.x & 1023) * 256 + threadIdx.x;
    const int n = idx & 1023;
    const int k0 = (idx >> 10) << 3;
    us8 o;
    #pragma unroll
    for (int j = 0; j < 8; ++j) o[j] = f2bf(w[(size_t)(k0 + j) * 1024 + n]);
    *(us8*)(wT + (size_t)n * 2048 + k0) = o;
}

// ---------------- 2. fused: motion score + window softmax + app/vid bf16 convert
// Early-exit when the chunk is entirely beyond this batch's valid length: those rows'
// outputs feed only masked (never-read) results downstream.
__global__ __launch_bounds__(256) void prep2_kernel(const float* __restrict__ clip_ft,
                                                    const int* __restrict__ lens,
                                                    const float* __restrict__ w_mot_wei,
                                                    const float* __restrict__ bsc,
                                                    unsigned short* __restrict__ app,   // [B][256][2048]
                                                    unsigned short* __restrict__ vid) { // [B][256][2048]
    __shared__ float sm2[2][4];
    const int b = blockIdx.x >> 3;
    const int c = blockIdx.x & 7;
    const int len = lens[b];
    const int l0 = c * 32;
    if (l0 >= len) return;                         // block-uniform: all rows masked downstream
    const int t = threadIdx.x;
    const int lane = t & 63, wv = t >> 6;
    const int d0 = t * 8;
    const float bias = bsc[0];
    const float* base = clip_ft + ((size_t)b * 256) * 2048 + d0;
    float wm[8];
    {
        f32x4 u = *(const f32x4*)(w_mot_wei + d0);
        f32x4 v = *(const f32x4*)(w_mot_wei + d0 + 4);
        #pragma unroll
        for (int j = 0; j < 4; ++j) { wm[j] = u[j]; wm[4 + j] = v[j]; }
    }
    float x0[8], x1[8], cur[8];
    float sc0 = NEGF, sc1 = NEGF, sc2 = NEGF;
    for (int i = 0; i < 34; ++i) {
        const int l = l0 + i;
        if (l < 256) {
            const f32x4* p = (const f32x4*)(base + (size_t)l * 2048);
            f32x4 u = p[0], v = p[1];
            #pragma unroll
            for (int j = 0; j < 4; ++j) { cur[j] = u[j]; cur[4 + j] = v[j]; }
            if (i < 32) {
                us8 o;
                #pragma unroll
                for (int j = 0; j < 8; ++j) o[j] = f2bf(cur[j]);
                *(us8*)(app + ((size_t)b * 256 + l) * 2048 + d0) = o;
            }
            float p8 = cur[0]*wm[0] + cur[1]*wm[1] + cur[2]*wm[2] + cur[3]*wm[3]
                     + cur[4]*wm[4] + cur[5]*wm[5] + cur[6]*wm[6] + cur[7]*wm[7];
            #pragma unroll
            for (int off = 32; off; off >>= 1) p8 += __shfl_xor(p8, off);
            if (lane == 0) sm2[i & 1][wv] = p8;
        }
        __syncthreads();                           // uniform; publishes sm2[i&1]
        if (l < 256) {
            float s = (sm2[i & 1][0] + sm2[i & 1][1]) + (sm2[i & 1][2] + sm2[i & 1][3]) + bias;
            sc2 = (l >= len) ? NEGF : s;
        }
        if (i >= 2) {
            const int lw = l - 2;
            if (lw < 254) {
                const float mx = fmaxf(sc0, fmaxf(sc1, sc2));
                const float e0 = expf(sc0 - mx), e1 = expf(sc1 - mx), e2 = expf(sc2 - mx);
                const float inv = 1.0f / (e0 + e1 + e2);
                const float a0 = e0 * inv, a1 = e1 * inv, a2 = e2 * inv;
                us8 o;
                #pragma unroll
                for (int j = 0; j < 8; ++j) o[j] = f2bf(a0 * x0[j] + a1 * x1[j] + a2 * cur[j]);
                *(us8*)(vid + ((size_t)b * 256 + lw) * 2048 + d0) = o;
            } else if (lw < 256) {
                us8 z = {};                         // zero pad rows 254,255
                *(us8*)(vid + ((size_t)b * 256 + lw) * 2048 + d0) = z;
            }
        }
        #pragma unroll
        for (int j = 0; j < 8; ++j) { x0[j] = x1[j]; x1[j] = cur[j]; }
        sc0 = sc1; sc1 = sc2;
    }
}

// ---------------- 3. fused dual bf16 MFMA GEMM — 128x256 tile, BK=32, 8 waves (2Mx4N,
// 64x64 per wave), 3 LDS bufs (72KB) depth-2 counted-vmcnt pipeline, 2 blocks/CU.
// R13: masked-tile skip — a 128-row stripe whose rows are all >= this batch's valid
// length produces only never-read outputs (pool softmax weight exactly 0); exit before
// staging. ~25% of tiles skipped at mean len~130. Stale bytes in skipped C/pspart rows
// are never read downstream (pool2 guards by `valid`).
__global__ __launch_bounds__(512, 4) void gemm3q_kernel(
        const unsigned short* __restrict__ Avid, const unsigned short* __restrict__ Aapp,
        const unsigned short* __restrict__ Bmot, const unsigned short* __restrict__ Bapp,
        const float* __restrict__ bmot, const float* __restrict__ bapp,
        const float* __restrict__ w_pool, const int* __restrict__ lens,
        unsigned short* __restrict__ Cmot, unsigned short* __restrict__ Capp,
        float* __restrict__ pspart) {             // [2][16384][16] strip partials
    __shared__ __align__(16) unsigned short lds_[3 * 12288]; // 72KB: 3 x (A 8KB | B 16KB)
    const int bid = blockIdx.x;
    const int virt = (bid & 7) * 128 + (bid >> 3);            // XCD-bijective
    const int which = virt >> 9;
    const int rem = virt & 511;
    const int mtile = rem >> 2, ntile = rem & 3;  // ntile fastest: B L2-resident per XCD
    const int row0 = mtile * 128, col0 = ntile * 256;
    const int batch = row0 >> 8;
    const int lim = lens[batch] - (which ? 0 : 2);
    if ((row0 & 255) >= lim) return;              // masked stripe: outputs never read
    const unsigned short* A  = which ? Aapp : Avid;
    const unsigned short* Bt = which ? Bapp : Bmot;
    const float* bias        = which ? bapp : bmot;
    unsigned short* C        = which ? Capp : Cmot;
    const int t = threadIdx.x, lane = t & 63, wave = t >> 6;
    const int wm = wave >> 2, wn = wave & 3;      // 2M x 4N waves, 64x64 each
    const int lr = lane & 15, sl = lane >> 4;     // frag row-in-16, k-slot 0..3

    // staging: thread t -> LDS[srow][t&3] linear; source k-slot pre-swizzled:
    // involution slot ^= (row>>1)&3 (conflicts=0)
    const int srow = t >> 2;                      // 0..127
    const int sk16 = (t & 3) ^ ((srow >> 1) & 3);
    const unsigned short* gA  = A  + (size_t)(row0 + srow) * GK + sk16 * 8;
    const unsigned short* gB0 = Bt + (size_t)(col0 + srow) * GK + sk16 * 8;        // cols 0-127
    const unsigned short* gB1 = Bt + (size_t)(col0 + srow + 128) * GK + sk16 * 8;  // cols 128-255
    const int wbase = wave << 9;                  // 1KB per wave within a call

#define STAGE(d, kt) do { \
    async_copy16(gA  + (kt) * 32, lds_ + (d) * 12288 +        wbase); \
    async_copy16(gB0 + (kt) * 32, lds_ + (d) * 12288 + 4096 + wbase); \
    async_copy16(gB1 + (kt) * 32, lds_ + (d) * 12288 + 8192 + wbase); } while (0)

#define KSTEP(CUR) do { \
    const unsigned short* lb = lds_ + (CUR) * 12288; \
    short8 aF[4], bF[4]; \
    _Pragma("unroll") \
    for (int m = 0; m < 4; ++m) { \
        const int r = wm * 64 + m * 16 + lr; \
        aF[m] = *(const short8*)(lb + r * 32 + ((sl ^ ((r >> 1) & 3)) << 3)); \
    } \
    _Pragma("unroll") \
    for (int n = 0; n < 4; ++n) { \
        const int cc = wn * 64 + n * 16 + lr; \
        bF[n] = *(const short8*)(lb + 4096 + cc * 32 + ((sl ^ ((cc >> 1) & 3)) << 3)); \
    } \
    _Pragma("unroll") \
    for (int m = 0; m < 4; ++m) \
        _Pragma("unroll") \
        for (int n = 0; n < 4; ++n) \
            acc[m][n] = __builtin_amdgcn_mfma_f32_16x16x32_bf16(aF[m], bF[n], acc[m][n], 0, 0, 0); \
    } while (0)

    f32x4 acc[4][4] = {};
    STAGE(0, 0);
    STAGE(1, 1);

    int cur = 0, stg = 2;
    #pragma unroll 3
    for (int kt = 0; kt < 62; ++kt) {
        // stage(kt) retired; stage(kt+1)'s 3 calls stay in flight
        asm volatile("s_waitcnt vmcnt(3)" ::: "memory");
        __builtin_amdgcn_s_barrier();
        __builtin_amdgcn_sched_barrier(0);
        STAGE(stg, kt + 2);                        // full compute phase of flight time
        KSTEP(cur);
        cur = (cur == 2) ? 0 : cur + 1;
        stg = (stg == 2) ? 0 : stg + 1;
    }
    // kt = 62: outstanding = stage(62) 3 + stage(63) 3
    asm volatile("s_waitcnt vmcnt(3)" ::: "memory");
    __builtin_amdgcn_s_barrier();
    __builtin_amdgcn_sched_barrier(0);
    KSTEP(cur);
    cur = (cur == 2) ? 0 : cur + 1;
    // kt = 63: drain
    asm volatile("s_waitcnt vmcnt(0)" ::: "memory");
    __builtin_amdgcn_s_barrier();
    __builtin_amdgcn_sched_barrier(0);
    KSTEP(cur);
#undef STAGE
#undef KSTEP

    // epilogue: C/D layout col=lane&15, row=(lane>>4)*4+i (HW-verified m89/m91)
    // + pool-dot partials per 64-col strip (strip = ntile*4 + wn), shfl-reduced over lr group
    float wp[4], bz[4];
    #pragma unroll
    for (int n = 0; n < 4; ++n) {
        const int col = col0 + wn * 64 + n * 16 + lr;
        wp[n] = w_pool[col];
        bz[n] = bias[col];
    }
    const int strip = ntile * 4 + wn;
    #pragma unroll
    for (int m = 0; m < 4; ++m) {
        #pragma unroll
        for (int i = 0; i < 4; ++i) {
            const int row = row0 + wm * 64 + m * 16 + sl * 4 + i;
            float pr = 0.f;
            #pragma unroll
            for (int n = 0; n < 4; ++n) {
                const int col = col0 + wn * 64 + n * 16 + lr;
                const float g = gelu_fast(acc[m][n][i] + bz[n]);
                pr += g * wp[n];
                C[(size_t)row * GN + col] = f2bf(g);
            }
            #pragma unroll
            for (int off = 8; off; off >>= 1) pr += __shfl_xor(pr, off);  // reduce over lr group
            if (lr == 0) pspart[((size_t)which * 16384 + row) * 16 + strip] = pr;
        }
    }
}

// ---------------- 4. masked softmax + weighted sum; block = (b, which); thread owns 4 cols
__global__ __launch_bounds__(256) void pool2_kernel(const unsigned short* __restrict__ motion,
                                                    const unsigned short* __restrict__ appearance,
                                                    const float* __restrict__ pspart,
                                                    const int* __restrict__ lens,
                                                    const float* __restrict__ b_pool,
                                                    float* __restrict__ out) {
    __shared__ float sm[256];
    __shared__ float red[8];
    const int which = blockIdx.x & 1;
    const int b = blockIdx.x >> 1;
    const unsigned short* mat = (which ? appearance : motion) + (size_t)b * 256 * 1024;
    const int valid = which ? lens[b] : lens[b] - 2;
    const int t = threadIdx.x, lane = t & 63, wv = t >> 6;
    float v = NEGF;
    if (t < valid) {
        const float* pp = pspart + ((size_t)which * 16384 + b * 256 + t) * 16;
        float s = 0.f;
        #pragma unroll
        for (int j = 0; j < 16; ++j) s += pp[j];
        v = gelu_erf(s + b_pool[0]);
    }
    float mx = v;
    #pragma unroll
    for (int off = 32; off; off >>= 1) mx = fmaxf(mx, __shfl_xor(mx, off));
    if (lane == 0) red[wv] = mx;
    __syncthreads();
    mx = fmaxf(fmaxf(red[0], red[1]), fmaxf(red[2], red[3]));
    const float e = expf(v - mx);                 // masked rows -> exactly 0
    float s = e;
    #pragma unroll
    for (int off = 32; off; off >>= 1) s += __shfl_xor(s, off);
    if (lane == 0) red[4 + wv] = s;
    __syncthreads();
    s = red[4] + red[5] + red[6] + red[7];
    sm[t] = e / s;
    __syncthreads();
    const int col0 = t * 4;
    float a0 = 0.f, a1 = 0.f, a2 = 0.f, a3 = 0.f;
    for (int l = 0; l < valid; ++l) {             // rows >= valid have weight exactly 0
        const float al = sm[l];
        us4 hv = *(const us4*)(mat + (size_t)l * 1024 + col0);
        a0 += al * bf2f(hv[0]);
        a1 += al * bf2f(hv[1]);
        a2 += al * bf2f(hv[2]);
        a3 += al * bf2f(hv[3]);
    }
    float* o = out + (size_t)b * 2048 + which * 1024 + col0;
    o[0] = a0; o[1] = a1; o[2] = a2; o[3] = a3;
}

extern "C" void kernel_launch(void* const* d_in, const int* in_sizes, int n_in,
                              void* d_out, int out_size, void* d_ws, size_t ws_size,
                              hipStream_t stream) {
    const float* clip_ft   = (const float*)d_in[0];
    const int*   clip_lens = (const int*)d_in[1];
    const float* w_mot_wei = (const float*)d_in[2];
    const float* b_mot_wei = (const float*)d_in[3];
    const float* w_mot_fc  = (const float*)d_in[4];
    const float* b_mot_fc  = (const float*)d_in[5];
    const float* w_app_fc  = (const float*)d_in[6];
    const float* b_app_fc  = (const float*)d_in[7];
    const float* w_pool    = (const float*)d_in[8];
    const float* b_pool    = (const float*)d_in[9];
    float* out = (float*)d_out;

    char* ws = (char*)d_ws;
    size_t off = 0;
    auto carve = [&](size_t bytes) { void* p = ws + off; off += (bytes + 255) & ~(size_t)255; return p; };
    float*          pspart = (float*)carve((size_t)2 * 16384 * 16 * 4);
    unsigned short* wmotT  = (unsigned short*)carve((size_t)1024 * 2048 * 2);
    unsigned short* wappT  = (unsigned short*)carve((size_t)1024 * 2048 * 2);
    unsigned short* appb   = (unsigned short*)carve((size_t)64 * 256 * 2048 * 2);
    unsigned short* vidb   = (unsigned short*)carve((size_t)64 * 256 * 2048 * 2);  // padded rows
    unsigned short* motion = (unsigned short*)carve((size_t)64 * 256 * 1024 * 2);  // padded rows
    unsigned short* appear = (unsigned short*)carve((size_t)64 * 256 * 1024 * 2);
    (void)ws_size; (void)in_sizes; (void)n_in; (void)out_size;

    wtrans2_kernel<<<2048, 256, 0, stream>>>(w_mot_fc, w_app_fc, wmotT, wappT);
    prep2_kernel<<<512, 256, 0, stream>>>(clip_ft, clip_lens, w_mot_wei, b_mot_wei, appb, vidb);
    gemm3q_kernel<<<1024, 512, 0, stream>>>(vidb, appb, wmotT, wappT,
                                            b_mot_fc, b_app_fc, w_pool, clip_lens,
                                            motion, appear, pspart);
    pool2_kernel<<<128, 256, 0, stream>>>(motion, appear, pspart, clip_lens, b_pool, out);
}

// Round 14
// 166.162 us; speedup vs baseline: 1.7769x; 1.3139x over previous
//
#include <hip/hip_runtime.h>
#include <cstdint>

#define NEGF (-1e18f)
#define GK 2048   // GEMM K
#define GN 1024   // GEMM N

typedef __attribute__((ext_vector_type(8))) short short8;     // 8 bf16 (4 VGPRs) MFMA A/B frag
typedef __attribute__((ext_vector_type(4))) float f32x4;      // MFMA C/D frag
typedef __attribute__((ext_vector_type(4))) unsigned short us4;
typedef __attribute__((ext_vector_type(8))) unsigned short us8;

__device__ __forceinline__ unsigned short f2bf(float f) {
    unsigned int u = __float_as_uint(f);
    u += 0x7FFFu + ((u >> 16) & 1u);          // RNE
    return (unsigned short)(u >> 16);
}
__device__ __forceinline__ float bf2f(unsigned short h) {
    return __uint_as_float(((unsigned int)h) << 16);
}
__device__ __forceinline__ float gelu_erf(float x) {
    return 0.5f * x * (1.0f + erff(x * 0.70710678118654752f));
}
// tanh-form GELU: max |diff| vs erf-GELU < 1e-3 (small vs 2.1e-2 threshold)
__device__ __forceinline__ float gelu_fast(float x) {
    const float y = 1.5957691216057308f * (x + 0.044715f * x * x * x);
    const float t = 1.0f - 2.0f / (__expf(y) + 1.0f);
    return 0.5f * x * (1.0f + t);
}
__device__ __forceinline__ void async_copy16(const void* g, void* l) {
    __builtin_amdgcn_global_load_lds(
        (const __attribute__((address_space(1))) unsigned int*)g,
        (__attribute__((address_space(3))) unsigned int*)l,
        16, 0, 0);
}

// ---------------- 0. prefix scan of valid lengths (compaction bases)
// bases[0..63]=base_mot, bases[64]=total_mot, bases[65..128]=base_app, bases[129]=total_app
__global__ __launch_bounds__(64) void scan_kernel(const int* __restrict__ lens,
                                                  int* __restrict__ bases) {
    const int lane = threadIdx.x;
    const int L = lens[lane];
    int sm_ = L - 2, sa_ = L;
    const int vm = sm_, va = sa_;
    #pragma unroll
    for (int off = 1; off < 64; off <<= 1) {
        const int tm = __shfl_up(sm_, off);
        const int ta = __shfl_up(sa_, off);
        if (lane >= off) { sm_ += tm; sa_ += ta; }
    }
    bases[lane] = sm_ - vm;                        // exclusive prefix (motion)
    bases[65 + lane] = sa_ - va;                   // exclusive prefix (appearance)
    if (lane == 63) { bases[64] = sm_; bases[129] = sa_; }
}

// ---------------- 1. weight transpose + bf16 convert (both weights in one dispatch)
__global__ __launch_bounds__(256) void wtrans2_kernel(const float* __restrict__ wmot,
                                                      const float* __restrict__ wapp,
                                                      unsigned short* __restrict__ wmotT,
                                                      unsigned short* __restrict__ wappT) {
    const int which = blockIdx.x >> 10;
    const float* w = which ? wapp : wmot;
    unsigned short* wT = which ? wappT : wmotT;
    const int idx = (blockIdx.x & 1023) * 256 + threadIdx.x;
    const int n = idx & 1023;
    const int k0 = (idx >> 10) << 3;
    us8 o;
    #pragma unroll
    for (int j = 0; j < 8; ++j) o[j] = f2bf(w[(size_t)(k0 + j) * 1024 + n]);
    *(us8*)(wT + (size_t)n * 2048 + k0) = o;
}

// ---------------- 2. fused: motion score + window softmax + COMPACTED app/vid bf16
// Valid rows written densely at base_app[b]+l / base_mot[b]+lw; masked rows not written.
__global__ __launch_bounds__(256) void prep2_kernel(const float* __restrict__ clip_ft,
                                                    const int* __restrict__ lens,
                                                    const int* __restrict__ bases,
                                                    const float* __restrict__ w_mot_wei,
                                                    const float* __restrict__ bsc,
                                                    unsigned short* __restrict__ app,   // compact [<=16384][2048]
                                                    unsigned short* __restrict__ vid) { // compact [<=16384][2048]
    __shared__ float sm2[2][4];
    const int b = blockIdx.x >> 3;
    const int c = blockIdx.x & 7;
    const int len = lens[b];
    const int l0 = c * 32;
    if (l0 >= len) return;                         // block-uniform: nothing valid here
    const int bm = bases[b], ba = bases[65 + b];
    const int t = threadIdx.x;
    const int lane = t & 63, wv = t >> 6;
    const int d0 = t * 8;
    const float bias = bsc[0];
    const float* base = clip_ft + ((size_t)b * 256) * 2048 + d0;
    float wm[8];
    {
        f32x4 u = *(const f32x4*)(w_mot_wei + d0);
        f32x4 v = *(const f32x4*)(w_mot_wei + d0 + 4);
        #pragma unroll
        for (int j = 0; j < 4; ++j) { wm[j] = u[j]; wm[4 + j] = v[j]; }
    }
    float x0[8], x1[8], cur[8];
    float sc0 = NEGF, sc1 = NEGF, sc2 = NEGF;
    for (int i = 0; i < 34; ++i) {
        const int l = l0 + i;
        if (l < 256) {
            const f32x4* p = (const f32x4*)(base + (size_t)l * 2048);
            f32x4 u = p[0], v = p[1];
            #pragma unroll
            for (int j = 0; j < 4; ++j) { cur[j] = u[j]; cur[4 + j] = v[j]; }
            if (i < 32 && l < len) {               // only valid rows, compact position
                us8 o;
                #pragma unroll
                for (int j = 0; j < 8; ++j) o[j] = f2bf(cur[j]);
                *(us8*)(app + ((size_t)(ba + l)) * 2048 + d0) = o;
            }
            float p8 = cur[0]*wm[0] + cur[1]*wm[1] + cur[2]*wm[2] + cur[3]*wm[3]
                     + cur[4]*wm[4] + cur[5]*wm[5] + cur[6]*wm[6] + cur[7]*wm[7];
            #pragma unroll
            for (int off = 32; off; off >>= 1) p8 += __shfl_xor(p8, off);
            if (lane == 0) sm2[i & 1][wv] = p8;
        }
        __syncthreads();                           // uniform; publishes sm2[i&1]
        if (l < 256) {
            float s = (sm2[i & 1][0] + sm2[i & 1][1]) + (sm2[i & 1][2] + sm2[i & 1][3]) + bias;
            sc2 = (l >= len) ? NEGF : s;
        }
        if (i >= 2) {
            const int lw = l - 2;
            if (lw < len - 2) {                    // only valid motion rows, compact position
                const float mx = fmaxf(sc0, fmaxf(sc1, sc2));
                const float e0 = expf(sc0 - mx), e1 = expf(sc1 - mx), e2 = expf(sc2 - mx);
                const float inv = 1.0f / (e0 + e1 + e2);
                const float a0 = e0 * inv, a1 = e1 * inv, a2 = e2 * inv;
                us8 o;
                #pragma unroll
                for (int j = 0; j < 8; ++j) o[j] = f2bf(a0 * x0[j] + a1 * x1[j] + a2 * cur[j]);
                *(us8*)(vid + ((size_t)(bm + lw)) * 2048 + d0) = o;
            }
        }
        #pragma unroll
        for (int j = 0; j < 8; ++j) { x0[j] = x1[j]; x1[j] = cur[j]; }
        sc0 = sc1; sc1 = sc2;
    }
}

// ---------------- 3. fused dual bf16 MFMA GEMM over COMPACT rows — 128x256 tile, BK=32,
// 8 waves (2Mx4N, 64x64/wave), 3 LDS bufs (72KB) depth-2 counted-vmcnt, 2 blocks/CU.
// Blocks with row0 >= total exit. mtile striding ((mt&31)*4+(mt>>5)) balances computed
// tiles across XCDs (compact totals ~ half of 16384 would otherwise idle 2 XCDs/problem).
// Tail-tile rows >= total stage stale-but-finite data; outputs land in never-read slots.
__global__ __launch_bounds__(512, 4) void gemm3q_kernel(
        const unsigned short* __restrict__ Avid, const unsigned short* __restrict__ Aapp,
        const unsigned short* __restrict__ Bmot, const unsigned short* __restrict__ Bapp,
        const float* __restrict__ bmot, const float* __restrict__ bapp,
        const float* __restrict__ w_pool, const int* __restrict__ bases,
        unsigned short* __restrict__ Cmot, unsigned short* __restrict__ Capp,
        float* __restrict__ pspart) {             // [2][16384][16] strip partials (compact rows)
    __shared__ __align__(16) unsigned short lds_[3 * 12288]; // 72KB: 3 x (A 8KB | B 16KB)
    const int bid = blockIdx.x;
    const int virt = (bid & 7) * 128 + (bid >> 3);            // XCD-bijective
    const int which = virt >> 9;
    const int rem = virt & 511;
    const int ntile = rem & 3;                    // ntile fastest: A-panel shared in-XCD
    const int mt_idx = rem >> 2;
    const int mtile = (mt_idx & 31) * 4 + (mt_idx >> 5);      // stride-4: balance across XCDs
    const int row0 = mtile * 128, col0 = ntile * 256;
    const int total = bases[which ? 129 : 64];
    if (row0 >= total) return;                    // beyond compacted rows: nothing to do
    const unsigned short* A  = which ? Aapp : Avid;
    const unsigned short* Bt = which ? Bapp : Bmot;
    const float* bias        = which ? bapp : bmot;
    unsigned short* C        = which ? Capp : Cmot;
    const int t = threadIdx.x, lane = t & 63, wave = t >> 6;
    const int wm = wave >> 2, wn = wave & 3;      // 2M x 4N waves, 64x64 each
    const int lr = lane & 15, sl = lane >> 4;     // frag row-in-16, k-slot 0..3

    // staging: thread t -> LDS[srow][t&3] linear; source k-slot pre-swizzled:
    // involution slot ^= (row>>1)&3 (conflicts=0)
    const int srow = t >> 2;                      // 0..127
    const int sk16 = (t & 3) ^ ((srow >> 1) & 3);
    const unsigned short* gA  = A  + (size_t)(row0 + srow) * GK + sk16 * 8;
    const unsigned short* gB0 = Bt + (size_t)(col0 + srow) * GK + sk16 * 8;        // cols 0-127
    const unsigned short* gB1 = Bt + (size_t)(col0 + srow + 128) * GK + sk16 * 8;  // cols 128-255
    const int wbase = wave << 9;                  // 1KB per wave within a call

#define STAGE(d, kt) do { \
    async_copy16(gA  + (kt) * 32, lds_ + (d) * 12288 +        wbase); \
    async_copy16(gB0 + (kt) * 32, lds_ + (d) * 12288 + 4096 + wbase); \
    async_copy16(gB1 + (kt) * 32, lds_ + (d) * 12288 + 8192 + wbase); } while (0)

#define KSTEP(CUR) do { \
    const unsigned short* lb = lds_ + (CUR) * 12288; \
    short8 aF[4], bF[4]; \
    _Pragma("unroll") \
    for (int m = 0; m < 4; ++m) { \
        const int r = wm * 64 + m * 16 + lr; \
        aF[m] = *(const short8*)(lb + r * 32 + ((sl ^ ((r >> 1) & 3)) << 3)); \
    } \
    _Pragma("unroll") \
    for (int n = 0; n < 4; ++n) { \
        const int cc = wn * 64 + n * 16 + lr; \
        bF[n] = *(const short8*)(lb + 4096 + cc * 32 + ((sl ^ ((cc >> 1) & 3)) << 3)); \
    } \
    _Pragma("unroll") \
    for (int m = 0; m < 4; ++m) \
        _Pragma("unroll") \
        for (int n = 0; n < 4; ++n) \
            acc[m][n] = __builtin_amdgcn_mfma_f32_16x16x32_bf16(aF[m], bF[n], acc[m][n], 0, 0, 0); \
    } while (0)

    f32x4 acc[4][4] = {};
    STAGE(0, 0);
    STAGE(1, 1);

    int cur = 0, stg = 2;
    #pragma unroll 3
    for (int kt = 0; kt < 62; ++kt) {
        // stage(kt) retired; stage(kt+1)'s 3 calls stay in flight
        asm volatile("s_waitcnt vmcnt(3)" ::: "memory");
        __builtin_amdgcn_s_barrier();
        __builtin_amdgcn_sched_barrier(0);
        STAGE(stg, kt + 2);                        // full compute phase of flight time
        KSTEP(cur);
        cur = (cur == 2) ? 0 : cur + 1;
        stg = (stg == 2) ? 0 : stg + 1;
    }
    // kt = 62: outstanding = stage(62) 3 + stage(63) 3
    asm volatile("s_waitcnt vmcnt(3)" ::: "memory");
    __builtin_amdgcn_s_barrier();
    __builtin_amdgcn_sched_barrier(0);
    KSTEP(cur);
    cur = (cur == 2) ? 0 : cur + 1;
    // kt = 63: drain
    asm volatile("s_waitcnt vmcnt(0)" ::: "memory");
    __builtin_amdgcn_s_barrier();
    __builtin_amdgcn_sched_barrier(0);
    KSTEP(cur);
#undef STAGE
#undef KSTEP

    // epilogue: C/D layout col=lane&15, row=(lane>>4)*4+i (HW-verified m89/m91)
    // + pool-dot partials per 64-col strip (strip = ntile*4 + wn), shfl-reduced over lr group
    float wp[4], bz[4];
    #pragma unroll
    for (int n = 0; n < 4; ++n) {
        const int col = col0 + wn * 64 + n * 16 + lr;
        wp[n] = w_pool[col];
        bz[n] = bias[col];
    }
    const int strip = ntile * 4 + wn;
    #pragma unroll
    for (int m = 0; m < 4; ++m) {
        #pragma unroll
        for (int i = 0; i < 4; ++i) {
            const int row = row0 + wm * 64 + m * 16 + sl * 4 + i;   // compact row
            float pr = 0.f;
            #pragma unroll
            for (int n = 0; n < 4; ++n) {
                const int col = col0 + wn * 64 + n * 16 + lr;
                const float g = gelu_fast(acc[m][n][i] + bz[n]);
                pr += g * wp[n];
                C[(size_t)row * GN + col] = f2bf(g);
            }
            #pragma unroll
            for (int off = 8; off; off >>= 1) pr += __shfl_xor(pr, off);  // reduce over lr group
            if (lr == 0) pspart[((size_t)which * 16384 + row) * 16 + strip] = pr;
        }
    }
}

// ---------------- 4. masked softmax + weighted sum over compact rows
__global__ __launch_bounds__(256) void pool2_kernel(const unsigned short* __restrict__ motion,
                                                    const unsigned short* __restrict__ appearance,
                                                    const float* __restrict__ pspart,
                                                    const int* __restrict__ lens,
                                                    const int* __restrict__ bases,
                                                    const float* __restrict__ b_pool,
                                                    float* __restrict__ out) {
    __shared__ float sm[256];
    __shared__ float red[8];
    const int which = blockIdx.x & 1;
    const int b = blockIdx.x >> 1;
    const int base = which ? bases[65 + b] : bases[b];
    const unsigned short* mat = (which ? appearance : motion) + (size_t)base * 1024;
    const int valid = which ? lens[b] : lens[b] - 2;
    const int t = threadIdx.x, lane = t & 63, wv = t >> 6;
    float v = NEGF;
    if (t < valid) {
        const float* pp = pspart + ((size_t)which * 16384 + base + t) * 16;
        float s = 0.f;
        #pragma unroll
        for (int j = 0; j < 16; ++j) s += pp[j];
        v = gelu_erf(s + b_pool[0]);
    }
    float mx = v;
    #pragma unroll
    for (int off = 32; off; off >>= 1) mx = fmaxf(mx, __shfl_xor(mx, off));
    if (lane == 0) red[wv] = mx;
    __syncthreads();
    mx = fmaxf(fmaxf(red[0], red[1]), fmaxf(red[2], red[3]));
    const float e = expf(v - mx);                 // masked rows -> exactly 0
    float s = e;
    #pragma unroll
    for (int off = 32; off; off >>= 1) s += __shfl_xor(s, off);
    if (lane == 0) red[4 + wv] = s;
    __syncthreads();
    s = red[4] + red[5] + red[6] + red[7];
    sm[t] = e / s;
    __syncthreads();
    const int col0 = t * 4;
    float a0 = 0.f, a1 = 0.f, a2 = 0.f, a3 = 0.f;
    for (int l = 0; l < valid; ++l) {             // rows >= valid have weight exactly 0
        const float al = sm[l];
        us4 hv = *(const us4*)(mat + (size_t)l * 1024 + col0);
        a0 += al * bf2f(hv[0]);
        a1 += al * bf2f(hv[1]);
        a2 += al * bf2f(hv[2]);
        a3 += al * bf2f(hv[3]);
    }
    float* o = out + (size_t)b * 2048 + which * 1024 + col0;
    o[0] = a0; o[1] = a1; o[2] = a2; o[3] = a3;
}

extern "C" void kernel_launch(void* const* d_in, const int* in_sizes, int n_in,
                              void* d_out, int out_size, void* d_ws, size_t ws_size,
                              hipStream_t stream) {
    const float* clip_ft   = (const float*)d_in[0];
    const int*   clip_lens = (const int*)d_in[1];
    const float* w_mot_wei = (const float*)d_in[2];
    const float* b_mot_wei = (const float*)d_in[3];
    const float* w_mot_fc  = (const float*)d_in[4];
    const float* b_mot_fc  = (const float*)d_in[5];
    const float* w_app_fc  = (const float*)d_in[6];
    const float* b_app_fc  = (const float*)d_in[7];
    const float* w_pool    = (const float*)d_in[8];
    const float* b_pool    = (const float*)d_in[9];
    float* out = (float*)d_out;

    char* ws = (char*)d_ws;
    size_t off = 0;
    auto carve = [&](size_t bytes) { void* p = ws + off; off += (bytes + 255) & ~(size_t)255; return p; };
    int*            bases  = (int*)carve((size_t)130 * 4);
    float*          pspart = (float*)carve((size_t)2 * 16384 * 16 * 4);
    unsigned short* wmotT  = (unsigned short*)carve((size_t)1024 * 2048 * 2);
    unsigned short* wappT  = (unsigned short*)carve((size_t)1024 * 2048 * 2);
    unsigned short* appb   = (unsigned short*)carve((size_t)64 * 256 * 2048 * 2);  // compact
    unsigned short* vidb   = (unsigned short*)carve((size_t)64 * 256 * 2048 * 2);  // compact
    unsigned short* motion = (unsigned short*)carve((size_t)64 * 256 * 1024 * 2);  // compact
    unsigned short* appear = (unsigned short*)carve((size_t)64 * 256 * 1024 * 2);  // compact
    (void)ws_size; (void)in_sizes; (void)n_in; (void)out_size;

    scan_kernel<<<1, 64, 0, stream>>>(clip_lens, bases);
    wtrans2_kernel<<<2048, 256, 0, stream>>>(w_mot_fc, w_app_fc, wmotT, wappT);
    prep2_kernel<<<512, 256, 0, stream>>>(clip_ft, clip_lens, bases, w_mot_wei, b_mot_wei,
                                          appb, vidb);
    gemm3q_kernel<<<1024, 512, 0, stream>>>(vidb, appb, wmotT, wappT,
                                            b_mot_fc, b_app_fc, w_pool, bases,
                                            motion, appear, pspart);
    pool2_kernel<<<128, 256, 0, stream>>>(motion, appear, pspart, clip_lens, bases, b_pool, out);
}

// Round 15
// 158.402 us; speedup vs baseline: 1.8640x; 1.0490x over previous
//
#include <hip/hip_runtime.h>
#include <cstdint>

#define NEGF (-1e18f)
#define GK 2048   // GEMM K
#define GN 1024   // GEMM N

typedef __attribute__((ext_vector_type(8))) short short8;     // 8 bf16 (4 VGPRs) MFMA A/B frag
typedef __attribute__((ext_vector_type(4))) float f32x4;      // MFMA C/D frag
typedef __attribute__((ext_vector_type(4))) unsigned short us4;
typedef __attribute__((ext_vector_type(8))) unsigned short us8;

__device__ __forceinline__ unsigned short f2bf(float f) {
    unsigned int u = __float_as_uint(f);
    u += 0x7FFFu + ((u >> 16) & 1u);          // RNE
    return (unsigned short)(u >> 16);
}
__device__ __forceinline__ float bf2f(unsigned short h) {
    return __uint_as_float(((unsigned int)h) << 16);
}
__device__ __forceinline__ float gelu_erf(float x) {
    return 0.5f * x * (1.0f + erff(x * 0.70710678118654752f));
}
// tanh-form GELU: max |diff| vs erf-GELU < 1e-3 (small vs 2.1e-2 threshold)
__device__ __forceinline__ float gelu_fast(float x) {
    const float y = 1.5957691216057308f * (x + 0.044715f * x * x * x);
    const float t = 1.0f - 2.0f / (__expf(y) + 1.0f);
    return 0.5f * x * (1.0f + t);
}
__device__ __forceinline__ void async_copy16(const void* g, void* l) {
    __builtin_amdgcn_global_load_lds(
        (const __attribute__((address_space(1))) unsigned int*)g,
        (__attribute__((address_space(3))) unsigned int*)l,
        16, 0, 0);
}

// ---------------- 1. weight transpose + bf16 convert; block 2048 = lens prefix scan
// bases[0..63]=base_mot, bases[64]=total_mot, bases[65..128]=base_app, bases[129]=total_app
__global__ __launch_bounds__(256) void wtrans2_kernel(const float* __restrict__ wmot,
                                                      const float* __restrict__ wapp,
                                                      const int* __restrict__ lens,
                                                      unsigned short* __restrict__ wmotT,
                                                      unsigned short* __restrict__ wappT,
                                                      int* __restrict__ bases) {
    if (blockIdx.x == 2048) {                     // prefix-scan block (64 active lanes)
        const int lane = threadIdx.x;
        if (lane < 64) {
            const int L = lens[lane];
            int sm_ = L - 2, sa_ = L;
            const int vm = sm_, va = sa_;
            #pragma unroll
            for (int off = 1; off < 64; off <<= 1) {
                const int tm = __shfl_up(sm_, off);
                const int ta = __shfl_up(sa_, off);
                if (lane >= off) { sm_ += tm; sa_ += ta; }
            }
            bases[lane] = sm_ - vm;               // exclusive prefix (motion)
            bases[65 + lane] = sa_ - va;          // exclusive prefix (appearance)
            if (lane == 63) { bases[64] = sm_; bases[129] = sa_; }
        }
        return;
    }
    const int which = blockIdx.x >> 10;
    const float* w = which ? wapp : wmot;
    unsigned short* wT = which ? wappT : wmotT;
    const int idx = (blockIdx.x & 1023) * 256 + threadIdx.x;
    const int n = idx & 1023;
    const int k0 = (idx >> 10) << 3;
    us8 o;
    #pragma unroll
    for (int j = 0; j < 8; ++j) o[j] = f2bf(w[(size_t)(k0 + j) * 1024 + n]);
    *(us8*)(wT + (size_t)n * 2048 + k0) = o;
}

// ---------------- 2. fused: motion score + window softmax + COMPACTED app/vid bf16
// Valid rows written densely at base_app[b]+l / base_mot[b]+lw; rows >= len never loaded
// (they feed no window: window lw <= len-3 touches rows <= len-1 only). All guards are
// block-uniform -> shfl/syncthreads stay convergent.
__global__ __launch_bounds__(256) void prep2_kernel(const float* __restrict__ clip_ft,
                                                    const int* __restrict__ lens,
                                                    const int* __restrict__ bases,
                                                    const float* __restrict__ w_mot_wei,
                                                    const float* __restrict__ bsc,
                                                    unsigned short* __restrict__ app,   // compact
                                                    unsigned short* __restrict__ vid) { // compact
    __shared__ float sm2[2][4];
    const int b = blockIdx.x >> 3;
    const int c = blockIdx.x & 7;
    const int len = lens[b];
    const int l0 = c * 32;
    if (l0 >= len) return;                         // block-uniform: nothing valid here
    const int bm = bases[b], ba = bases[65 + b];
    const int t = threadIdx.x;
    const int lane = t & 63, wv = t >> 6;
    const int d0 = t * 8;
    const float bias = bsc[0];
    const float* base = clip_ft + ((size_t)b * 256) * 2048 + d0;
    float wm[8];
    {
        f32x4 u = *(const f32x4*)(w_mot_wei + d0);
        f32x4 v = *(const f32x4*)(w_mot_wei + d0 + 4);
        #pragma unroll
        for (int j = 0; j < 4; ++j) { wm[j] = u[j]; wm[4 + j] = v[j]; }
    }
    float x0[8], x1[8], cur[8];
    float sc0 = NEGF, sc1 = NEGF, sc2 = NEGF;
    for (int i = 0; i < 34; ++i) {
        const int l = l0 + i;
        const bool live = (l < len);               // block-uniform (l,len uniform)
        if (live) {
            const f32x4* p = (const f32x4*)(base + (size_t)l * 2048);
            f32x4 u = p[0], v = p[1];
            #pragma unroll
            for (int j = 0; j < 4; ++j) { cur[j] = u[j]; cur[4 + j] = v[j]; }
            if (i < 32) {                          // compact app write (valid rows only)
                us8 o;
                #pragma unroll
                for (int j = 0; j < 8; ++j) o[j] = f2bf(cur[j]);
                *(us8*)(app + ((size_t)(ba + l)) * 2048 + d0) = o;
            }
            float p8 = cur[0]*wm[0] + cur[1]*wm[1] + cur[2]*wm[2] + cur[3]*wm[3]
                     + cur[4]*wm[4] + cur[5]*wm[5] + cur[6]*wm[6] + cur[7]*wm[7];
            #pragma unroll
            for (int off = 32; off; off >>= 1) p8 += __shfl_xor(p8, off);
            if (lane == 0) sm2[i & 1][wv] = p8;
        }
        __syncthreads();                           // uniform; publishes sm2[i&1]
        sc2 = live ? (sm2[i & 1][0] + sm2[i & 1][1]) + (sm2[i & 1][2] + sm2[i & 1][3]) + bias
                   : NEGF;
        if (i >= 2) {
            const int lw = l - 2;
            if (lw < len - 2) {                    // valid motion rows only, compact position
                const float mx = fmaxf(sc0, fmaxf(sc1, sc2));
                const float e0 = expf(sc0 - mx), e1 = expf(sc1 - mx), e2 = expf(sc2 - mx);
                const float inv = 1.0f / (e0 + e1 + e2);
                const float a0 = e0 * inv, a1 = e1 * inv, a2 = e2 * inv;
                us8 o;
                #pragma unroll
                for (int j = 0; j < 8; ++j) o[j] = f2bf(a0 * x0[j] + a1 * x1[j] + a2 * cur[j]);
                *(us8*)(vid + ((size_t)(bm + lw)) * 2048 + d0) = o;
            }
        }
        #pragma unroll
        for (int j = 0; j < 8; ++j) { x0[j] = x1[j]; x1[j] = cur[j]; }
        sc0 = sc1; sc1 = sc2;
    }
}

// ---------------- 3. fused dual bf16 MFMA GEMM over COMPACT rows — 128x256 tile, BK=32,
// 8 waves (2Mx4N, 64x64/wave), 3 LDS bufs (72KB) depth-2 counted-vmcnt, 2 blocks/CU
// (register-capped: acc 64 AGPR + 64 VGPR = 128 total -> 4 waves/EU max).
__global__ __launch_bounds__(512, 4) void gemm3q_kernel(
        const unsigned short* __restrict__ Avid, const unsigned short* __restrict__ Aapp,
        const unsigned short* __restrict__ Bmot, const unsigned short* __restrict__ Bapp,
        const float* __restrict__ bmot, const float* __restrict__ bapp,
        const float* __restrict__ w_pool, const int* __restrict__ bases,
        unsigned short* __restrict__ Cmot, unsigned short* __restrict__ Capp,
        float* __restrict__ pspart) {             // [2][16384][16] strip partials (compact rows)
    __shared__ __align__(16) unsigned short lds_[3 * 12288]; // 72KB: 3 x (A 8KB | B 16KB)
    const int bid = blockIdx.x;
    const int virt = (bid & 7) * 128 + (bid >> 3);            // XCD-bijective
    const int which = virt >> 9;
    const int rem = virt & 511;
    const int ntile = rem & 3;                    // ntile fastest: A-panel shared in-XCD
    const int mt_idx = rem >> 2;
    const int mtile = (mt_idx & 31) * 4 + (mt_idx >> 5);      // stride-4: balance across XCDs
    const int row0 = mtile * 128, col0 = ntile * 256;
    const int total = bases[which ? 129 : 64];
    if (row0 >= total) return;                    // beyond compacted rows: nothing to do
    const unsigned short* A  = which ? Aapp : Avid;
    const unsigned short* Bt = which ? Bapp : Bmot;
    const float* bias        = which ? bapp : bmot;
    unsigned short* C        = which ? Capp : Cmot;
    const int t = threadIdx.x, lane = t & 63, wave = t >> 6;
    const int wm = wave >> 2, wn = wave & 3;      // 2M x 4N waves, 64x64 each
    const int lr = lane & 15, sl = lane >> 4;     // frag row-in-16, k-slot 0..3

    // staging: thread t -> LDS[srow][t&3] linear; source k-slot pre-swizzled:
    // involution slot ^= (row>>1)&3 (conflicts=0)
    const int srow = t >> 2;                      // 0..127
    const int sk16 = (t & 3) ^ ((srow >> 1) & 3);
    const unsigned short* gA  = A  + (size_t)(row0 + srow) * GK + sk16 * 8;
    const unsigned short* gB0 = Bt + (size_t)(col0 + srow) * GK + sk16 * 8;        // cols 0-127
    const unsigned short* gB1 = Bt + (size_t)(col0 + srow + 128) * GK + sk16 * 8;  // cols 128-255
    const int wbase = wave << 9;                  // 1KB per wave within a call

#define STAGE(d, kt) do { \
    async_copy16(gA  + (kt) * 32, lds_ + (d) * 12288 +        wbase); \
    async_copy16(gB0 + (kt) * 32, lds_ + (d) * 12288 + 4096 + wbase); \
    async_copy16(gB1 + (kt) * 32, lds_ + (d) * 12288 + 8192 + wbase); } while (0)

#define KSTEP(CUR) do { \
    const unsigned short* lb = lds_ + (CUR) * 12288; \
    short8 aF[4], bF[4]; \
    _Pragma("unroll") \
    for (int m = 0; m < 4; ++m) { \
        const int r = wm * 64 + m * 16 + lr; \
        aF[m] = *(const short8*)(lb + r * 32 + ((sl ^ ((r >> 1) & 3)) << 3)); \
    } \
    _Pragma("unroll") \
    for (int n = 0; n < 4; ++n) { \
        const int cc = wn * 64 + n * 16 + lr; \
        bF[n] = *(const short8*)(lb + 4096 + cc * 32 + ((sl ^ ((cc >> 1) & 3)) << 3)); \
    } \
    _Pragma("unroll") \
    for (int m = 0; m < 4; ++m) \
        _Pragma("unroll") \
        for (int n = 0; n < 4; ++n) \
            acc[m][n] = __builtin_amdgcn_mfma_f32_16x16x32_bf16(aF[m], bF[n], acc[m][n], 0, 0, 0); \
    } while (0)

    f32x4 acc[4][4] = {};
    STAGE(0, 0);
    STAGE(1, 1);

    int cur = 0, stg = 2;
    #pragma unroll 3
    for (int kt = 0; kt < 62; ++kt) {
        // stage(kt) retired; stage(kt+1)'s 3 calls stay in flight
        asm volatile("s_waitcnt vmcnt(3)" ::: "memory");
        __builtin_amdgcn_s_barrier();
        __builtin_amdgcn_sched_barrier(0);
        STAGE(stg, kt + 2);                        // full compute phase of flight time
        KSTEP(cur);
        cur = (cur == 2) ? 0 : cur + 1;
        stg = (stg == 2) ? 0 : stg + 1;
    }
    // kt = 62: outstanding = stage(62) 3 + stage(63) 3
    asm volatile("s_waitcnt vmcnt(3)" ::: "memory");
    __builtin_amdgcn_s_barrier();
    __builtin_amdgcn_sched_barrier(0);
    KSTEP(cur);
    cur = (cur == 2) ? 0 : cur + 1;
    // kt = 63: drain
    asm volatile("s_waitcnt vmcnt(0)" ::: "memory");
    __builtin_amdgcn_s_barrier();
    __builtin_amdgcn_sched_barrier(0);
    KSTEP(cur);
#undef STAGE
#undef KSTEP

    // epilogue: C/D layout col=lane&15, row=(lane>>4)*4+i (HW-verified m89/m91)
    // + pool-dot partials per 64-col strip (strip = ntile*4 + wn), shfl-reduced over lr group
    float wp[4], bz[4];
    #pragma unroll
    for (int n = 0; n < 4; ++n) {
        const int col = col0 + wn * 64 + n * 16 + lr;
        wp[n] = w_pool[col];
        bz[n] = bias[col];
    }
    const int strip = ntile * 4 + wn;
    #pragma unroll
    for (int m = 0; m < 4; ++m) {
        #pragma unroll
        for (int i = 0; i < 4; ++i) {
            const int row = row0 + wm * 64 + m * 16 + sl * 4 + i;   // compact row
            float pr = 0.f;
            #pragma unroll
            for (int n = 0; n < 4; ++n) {
                const int col = col0 + wn * 64 + n * 16 + lr;
                const float g = gelu_fast(acc[m][n][i] + bz[n]);
                pr += g * wp[n];
                C[(size_t)row * GN + col] = f2bf(g);
            }
            #pragma unroll
            for (int off = 8; off; off >>= 1) pr += __shfl_xor(pr, off);  // reduce over lr group
            if (lr == 0) pspart[((size_t)which * 16384 + row) * 16 + strip] = pr;
        }
    }
}

// ---------------- 4. masked softmax + weighted sum over compact rows
// block = (b, which, col-half); thread owns 2 cols -> 256 blocks (2x CU fill of R14)
__global__ __launch_bounds__(256) void pool2_kernel(const unsigned short* __restrict__ motion,
                                                    const unsigned short* __restrict__ appearance,
                                                    const float* __restrict__ pspart,
                                                    const int* __restrict__ lens,
                                                    const int* __restrict__ bases,
                                                    const float* __restrict__ b_pool,
                                                    float* __restrict__ out) {
    __shared__ float sm[256];
    __shared__ float red[8];
    const int which = blockIdx.x & 1;
    const int half = (blockIdx.x >> 1) & 1;
    const int b = blockIdx.x >> 2;
    const int base = which ? bases[65 + b] : bases[b];
    const unsigned short* mat = (which ? appearance : motion) + (size_t)base * 1024;
    const int valid = which ? lens[b] : lens[b] - 2;
    const int t = threadIdx.x, lane = t & 63, wv = t >> 6;
    float v = NEGF;
    if (t < valid) {
        const float* pp = pspart + ((size_t)which * 16384 + base + t) * 16;
        float s = 0.f;
        #pragma unroll
        for (int j = 0; j < 16; ++j) s += pp[j];
        v = gelu_erf(s + b_pool[0]);
    }
    float mx = v;
    #pragma unroll
    for (int off = 32; off; off >>= 1) mx = fmaxf(mx, __shfl_xor(mx, off));
    if (lane == 0) red[wv] = mx;
    __syncthreads();
    mx = fmaxf(fmaxf(red[0], red[1]), fmaxf(red[2], red[3]));
    const float e = expf(v - mx);                 // masked rows -> exactly 0
    float s = e;
    #pragma unroll
    for (int off = 32; off; off >>= 1) s += __shfl_xor(s, off);
    if (lane == 0) red[4 + wv] = s;
    __syncthreads();
    s = red[4] + red[5] + red[6] + red[7];
    sm[t] = e / s;
    __syncthreads();
    const int col0 = half * 512 + t * 2;
    float a0 = 0.f, a1 = 0.f;
    for (int l = 0; l < valid; ++l) {             // rows >= valid have weight exactly 0
        const float al = sm[l];
        const unsigned int hv = *(const unsigned int*)(mat + (size_t)l * 1024 + col0);
        a0 += al * bf2f((unsigned short)(hv & 0xFFFF));
        a1 += al * bf2f((unsigned short)(hv >> 16));
    }
    float* o = out + (size_t)b * 2048 + which * 1024 + col0;
    o[0] = a0; o[1] = a1;
}

extern "C" void kernel_launch(void* const* d_in, const int* in_sizes, int n_in,
                              void* d_out, int out_size, void* d_ws, size_t ws_size,
                              hipStream_t stream) {
    const float* clip_ft   = (const float*)d_in[0];
    const int*   clip_lens = (const int*)d_in[1];
    const float* w_mot_wei = (const float*)d_in[2];
    const float* b_mot_wei = (const float*)d_in[3];
    const float* w_mot_fc  = (const float*)d_in[4];
    const float* b_mot_fc  = (const float*)d_in[5];
    const float* w_app_fc  = (const float*)d_in[6];
    const float* b_app_fc  = (const float*)d_in[7];
    const float* w_pool    = (const float*)d_in[8];
    const float* b_pool    = (const float*)d_in[9];
    float* out = (float*)d_out;

    char* ws = (char*)d_ws;
    size_t off = 0;
    auto carve = [&](size_t bytes) { void* p = ws + off; off += (bytes + 255) & ~(size_t)255; return p; };
    int*            bases  = (int*)carve((size_t)130 * 4);
    float*          pspart = (float*)carve((size_t)2 * 16384 * 16 * 4);
    unsigned short* wmotT  = (unsigned short*)carve((size_t)1024 * 2048 * 2);
    unsigned short* wappT  = (unsigned short*)carve((size_t)1024 * 2048 * 2);
    unsigned short* appb   = (unsigned short*)carve((size_t)64 * 256 * 2048 * 2);  // compact
    unsigned short* vidb   = (unsigned short*)carve((size_t)64 * 256 * 2048 * 2);  // compact
    unsigned short* motion = (unsigned short*)carve((size_t)64 * 256 * 1024 * 2);  // compact
    unsigned short* appear = (unsigned short*)carve((size_t)64 * 256 * 1024 * 2);  // compact
    (void)ws_size; (void)in_sizes; (void)n_in; (void)out_size;

    wtrans2_kernel<<<2049, 256, 0, stream>>>(w_mot_fc, w_app_fc, clip_lens,
                                             wmotT, wappT, bases);
    prep2_kernel<<<512, 256, 0, stream>>>(clip_ft, clip_lens, bases, w_mot_wei, b_mot_wei,
                                          appb, vidb);
    gemm3q_kernel<<<1024, 512, 0, stream>>>(vidb, appb, wmotT, wappT,
                                            b_mot_fc, b_app_fc, w_pool, bases,
                                            motion, appear, pspart);
    pool2_kernel<<<256, 256, 0, stream>>>(motion, appear, pspart, clip_lens, bases, b_pool, out);
}

// Round 16
// 155.090 us; speedup vs baseline: 1.9038x; 1.0214x over previous
//
#include <hip/hip_runtime.h>
#include <cstdint>

#define NEGF (-1e18f)
#define GK 2048   // GEMM K
#define GN 1024   // GEMM N

typedef __attribute__((ext_vector_type(8))) short short8;     // 8 bf16 (4 VGPRs) MFMA A/B frag
typedef __attribute__((ext_vector_type(4))) float f32x4;      // MFMA C/D frag
typedef __attribute__((ext_vector_type(4))) unsigned short us4;
typedef __attribute__((ext_vector_type(8))) unsigned short us8;

__device__ __forceinline__ unsigned short f2bf(float f) {
    unsigned int u = __float_as_uint(f);
    u += 0x7FFFu + ((u >> 16) & 1u);          // RNE
    return (unsigned short)(u >> 16);
}
__device__ __forceinline__ float bf2f(unsigned short h) {
    return __uint_as_float(((unsigned int)h) << 16);
}
__device__ __forceinline__ float gelu_erf(float x) {
    return 0.5f * x * (1.0f + erff(x * 0.70710678118654752f));
}
// tanh-form GELU: max |diff| vs erf-GELU < 1e-3 (small vs 2.1e-2 threshold)
__device__ __forceinline__ float gelu_fast(float x) {
    const float y = 1.5957691216057308f * (x + 0.044715f * x * x * x);
    const float t = 1.0f - 2.0f / (__expf(y) + 1.0f);
    return 0.5f * x * (1.0f + t);
}
__device__ __forceinline__ void async_copy16(const void* g, void* l) {
    __builtin_amdgcn_global_load_lds(
        (const __attribute__((address_space(1))) unsigned int*)g,
        (__attribute__((address_space(3))) unsigned int*)l,
        16, 0, 0);
}

// ---------------- 1. FUSED: weight transpose (blocks 0..2047) + prep (blocks 2048..2559)
// prep: motion score + window softmax + COMPACTED app/vid bf16, with register prefetch of
// the next row so HBM latency hides under the score reduce+sync. Compaction bases are
// recomputed locally (64-lane shfl scan, ~100cyc) — no scan kernel, no dependency.
__global__ __launch_bounds__(256) void fused1_kernel(const float* __restrict__ wmot,
                                                     const float* __restrict__ wapp,
                                                     const float* __restrict__ clip_ft,
                                                     const int* __restrict__ lens,
                                                     const float* __restrict__ w_mot_wei,
                                                     const float* __restrict__ bsc,
                                                     unsigned short* __restrict__ wmotT,
                                                     unsigned short* __restrict__ wappT,
                                                     unsigned short* __restrict__ app,   // compact
                                                     unsigned short* __restrict__ vid) { // compact
    if (blockIdx.x < 2048) {                       // ---- weight transpose + bf16 convert
        const int which = blockIdx.x >> 10;
        const float* w = which ? wapp : wmot;
        unsigned short* wT = which ? wappT : wmotT;
        const int idx = (blockIdx.x & 1023) * 256 + threadIdx.x;
        const int n = idx & 1023;
        const int k0 = (idx >> 10) << 3;
        us8 o;
        #pragma unroll
        for (int j = 0; j < 8; ++j) o[j] = f2bf(w[(size_t)(k0 + j) * 1024 + n]);
        *(us8*)(wT + (size_t)n * 2048 + k0) = o;
        return;
    }
    // ---- prep part
    __shared__ float sm2[2][4];
    __shared__ int sb2[2];
    const int bid = blockIdx.x - 2048;
    const int b = bid >> 3;
    const int c = bid & 7;
    const int len = lens[b];
    const int l0 = c * 32;
    if (l0 >= len) return;                         // block-uniform: nothing valid here
    const int t = threadIdx.x;
    if (t < 64) {                                  // local compaction-base scan (wave 0)
        const int L2 = lens[t];
        const int m0 = L2 - 2, a0 = L2;
        int mi = m0, ai = a0;
        #pragma unroll
        for (int off = 1; off < 64; off <<= 1) {
            const int tm = __shfl_up(mi, off);
            const int ta = __shfl_up(ai, off);
            if (t >= off) { mi += tm; ai += ta; }
        }
        if (t == b) { sb2[0] = mi - m0; sb2[1] = ai - a0; }
    }
    const int lane = t & 63, wv = t >> 6;
    const int d0 = t * 8;
    const float bias = bsc[0];
    const float* base = clip_ft + ((size_t)b * 256) * 2048 + d0;
    float wm[8];
    {
        f32x4 u = *(const f32x4*)(w_mot_wei + d0);
        f32x4 v = *(const f32x4*)(w_mot_wei + d0 + 4);
        #pragma unroll
        for (int j = 0; j < 4; ++j) { wm[j] = u[j]; wm[4 + j] = v[j]; }
    }
    __syncthreads();                               // publishes sb2
    const int bm = sb2[0], ba = sb2[1];
    float x0[8], x1[8], cur[8], nxt[8];
    {                                              // preload row l0 (live by construction)
        const f32x4* p = (const f32x4*)(base + (size_t)l0 * 2048);
        f32x4 u = p[0], v = p[1];
        #pragma unroll
        for (int j = 0; j < 4; ++j) { cur[j] = u[j]; cur[4 + j] = v[j]; }
    }
    float sc0 = NEGF, sc1 = NEGF, sc2 = NEGF;
    for (int i = 0; i < 34; ++i) {
        const int l = l0 + i;
        const bool live = (l < len);               // block-uniform
        const bool liveN = (i < 33) && (l + 1 < len);
        if (liveN) {                               // prefetch next row: flies under reduce+sync
            const f32x4* p = (const f32x4*)(base + (size_t)(l + 1) * 2048);
            f32x4 u = p[0], v = p[1];
            #pragma unroll
            for (int j = 0; j < 4; ++j) { nxt[j] = u[j]; nxt[4 + j] = v[j]; }
        }
        if (live) {
            if (i < 32) {                          // compact app write (valid rows only)
                us8 o;
                #pragma unroll
                for (int j = 0; j < 8; ++j) o[j] = f2bf(cur[j]);
                *(us8*)(app + ((size_t)(ba + l)) * 2048 + d0) = o;
            }
            float p8 = cur[0]*wm[0] + cur[1]*wm[1] + cur[2]*wm[2] + cur[3]*wm[3]
                     + cur[4]*wm[4] + cur[5]*wm[5] + cur[6]*wm[6] + cur[7]*wm[7];
            #pragma unroll
            for (int off = 32; off; off >>= 1) p8 += __shfl_xor(p8, off);
            if (lane == 0) sm2[i & 1][wv] = p8;
        }
        __syncthreads();                           // uniform; publishes sm2[i&1]
        sc2 = live ? (sm2[i & 1][0] + sm2[i & 1][1]) + (sm2[i & 1][2] + sm2[i & 1][3]) + bias
                   : NEGF;
        if (i >= 2) {
            const int lw = l - 2;
            if (lw < len - 2) {                    // valid motion rows only, compact position
                const float mx = fmaxf(sc0, fmaxf(sc1, sc2));
                const float e0 = expf(sc0 - mx), e1 = expf(sc1 - mx), e2 = expf(sc2 - mx);
                const float inv = 1.0f / (e0 + e1 + e2);
                const float a0 = e0 * inv, a1 = e1 * inv, a2 = e2 * inv;
                us8 o;
                #pragma unroll
                for (int j = 0; j < 8; ++j) o[j] = f2bf(a0 * x0[j] + a1 * x1[j] + a2 * cur[j]);
                *(us8*)(vid + ((size_t)(bm + lw)) * 2048 + d0) = o;
            }
        }
        #pragma unroll
        for (int j = 0; j < 8; ++j) { x0[j] = x1[j]; x1[j] = cur[j]; if (liveN) cur[j] = nxt[j]; }
        sc0 = sc1; sc1 = sc2;
    }
}

// ---------------- 2. fused dual bf16 MFMA GEMM over COMPACT rows — 128x256 tile, BK=32,
// 8 waves (2Mx4N, 64x64/wave), 3 LDS bufs (72KB) depth-2 counted-vmcnt, 2 blocks/CU
// (register-capped: acc 64 AGPR + 64 VGPR = 128 total -> 4 waves/EU max).
__global__ __launch_bounds__(512, 4) void gemm3q_kernel(
        const unsigned short* __restrict__ Avid, const unsigned short* __restrict__ Aapp,
        const unsigned short* __restrict__ Bmot, const unsigned short* __restrict__ Bapp,
        const float* __restrict__ bmot, const float* __restrict__ bapp,
        const float* __restrict__ w_pool, const int* __restrict__ lens,
        unsigned short* __restrict__ Cmot, unsigned short* __restrict__ Capp,
        float* __restrict__ pspart) {             // [2][16384][16] strip partials (compact rows)
    __shared__ __align__(16) unsigned short lds_[3 * 12288]; // 72KB: 3 x (A 8KB | B 16KB)
    __shared__ int stot;
    const int bid = blockIdx.x;
    const int virt = (bid & 7) * 128 + (bid >> 3);            // XCD-bijective
    const int which = virt >> 9;
    const int rem = virt & 511;
    const int ntile = rem & 3;                    // ntile fastest: A-panel shared in-XCD
    const int mt_idx = rem >> 2;
    const int mtile = (mt_idx & 31) * 4 + (mt_idx >> 5);      // stride-4: balance across XCDs
    const int row0 = mtile * 128, col0 = ntile * 256;
    if (threadIdx.x < 64) {                       // local total (wave 0)
        int v = lens[threadIdx.x] - (which ? 0 : 2);
        #pragma unroll
        for (int off = 32; off; off >>= 1) v += __shfl_xor(v, off);
        if (threadIdx.x == 0) stot = v;
    }
    __syncthreads();
    if (row0 >= stot) return;                     // beyond compacted rows: nothing to do
    const unsigned short* A  = which ? Aapp : Avid;
    const unsigned short* Bt = which ? Bapp : Bmot;
    const float* bias        = which ? bapp : bmot;
    unsigned short* C        = which ? Capp : Cmot;
    const int t = threadIdx.x, lane = t & 63, wave = t >> 6;
    const int wm = wave >> 2, wn = wave & 3;      // 2M x 4N waves, 64x64 each
    const int lr = lane & 15, sl = lane >> 4;     // frag row-in-16, k-slot 0..3

    // staging: thread t -> LDS[srow][t&3] linear; source k-slot pre-swizzled:
    // involution slot ^= (row>>1)&3 (conflicts=0)
    const int srow = t >> 2;                      // 0..127
    const int sk16 = (t & 3) ^ ((srow >> 1) & 3);
    const unsigned short* gA  = A  + (size_t)(row0 + srow) * GK + sk16 * 8;
    const unsigned short* gB0 = Bt + (size_t)(col0 + srow) * GK + sk16 * 8;        // cols 0-127
    const unsigned short* gB1 = Bt + (size_t)(col0 + srow + 128) * GK + sk16 * 8;  // cols 128-255
    const int wbase = wave << 9;                  // 1KB per wave within a call

#define STAGE(d, kt) do { \
    async_copy16(gA  + (kt) * 32, lds_ + (d) * 12288 +        wbase); \
    async_copy16(gB0 + (kt) * 32, lds_ + (d) * 12288 + 4096 + wbase); \
    async_copy16(gB1 + (kt) * 32, lds_ + (d) * 12288 + 8192 + wbase); } while (0)

#define KSTEP(CUR) do { \
    const unsigned short* lb = lds_ + (CUR) * 12288; \
    short8 aF[4], bF[4]; \
    _Pragma("unroll") \
    for (int m = 0; m < 4; ++m) { \
        const int r = wm * 64 + m * 16 + lr; \
        aF[m] = *(const short8*)(lb + r * 32 + ((sl ^ ((r >> 1) & 3)) << 3)); \
    } \
    _Pragma("unroll") \
    for (int n = 0; n < 4; ++n) { \
        const int cc = wn * 64 + n * 16 + lr; \
        bF[n] = *(const short8*)(lb + 4096 + cc * 32 + ((sl ^ ((cc >> 1) & 3)) << 3)); \
    } \
    _Pragma("unroll") \
    for (int m = 0; m < 4; ++m) \
        _Pragma("unroll") \
        for (int n = 0; n < 4; ++n) \
            acc[m][n] = __builtin_amdgcn_mfma_f32_16x16x32_bf16(aF[m], bF[n], acc[m][n], 0, 0, 0); \
    } while (0)

    f32x4 acc[4][4] = {};
    STAGE(0, 0);
    STAGE(1, 1);

    int cur = 0, stg = 2;
    #pragma unroll 3
    for (int kt = 0; kt < 62; ++kt) {
        // stage(kt) retired; stage(kt+1)'s 3 calls stay in flight
        asm volatile("s_waitcnt vmcnt(3)" ::: "memory");
        __builtin_amdgcn_s_barrier();
        __builtin_amdgcn_sched_barrier(0);
        STAGE(stg, kt + 2);                        // full compute phase of flight time
        KSTEP(cur);
        cur = (cur == 2) ? 0 : cur + 1;
        stg = (stg == 2) ? 0 : stg + 1;
    }
    // kt = 62: outstanding = stage(62) 3 + stage(63) 3
    asm volatile("s_waitcnt vmcnt(3)" ::: "memory");
    __builtin_amdgcn_s_barrier();
    __builtin_amdgcn_sched_barrier(0);
    KSTEP(cur);
    cur = (cur == 2) ? 0 : cur + 1;
    // kt = 63: drain
    asm volatile("s_waitcnt vmcnt(0)" ::: "memory");
    __builtin_amdgcn_s_barrier();
    __builtin_amdgcn_sched_barrier(0);
    KSTEP(cur);
#undef STAGE
#undef KSTEP

    // epilogue: C/D layout col=lane&15, row=(lane>>4)*4+i (HW-verified m89/m91)
    // + pool-dot partials per 64-col strip (strip = ntile*4 + wn), shfl-reduced over lr group
    float wp[4], bz[4];
    #pragma unroll
    for (int n = 0; n < 4; ++n) {
        const int col = col0 + wn * 64 + n * 16 + lr;
        wp[n] = w_pool[col];
        bz[n] = bias[col];
    }
    const int strip = ntile * 4 + wn;
    #pragma unroll
    for (int m = 0; m < 4; ++m) {
        #pragma unroll
        for (int i = 0; i < 4; ++i) {
            const int row = row0 + wm * 64 + m * 16 + sl * 4 + i;   // compact row
            float pr = 0.f;
            #pragma unroll
            for (int n = 0; n < 4; ++n) {
                const int col = col0 + wn * 64 + n * 16 + lr;
                const float g = gelu_fast(acc[m][n][i] + bz[n]);
                pr += g * wp[n];
                C[(size_t)row * GN + col] = f2bf(g);
            }
            #pragma unroll
            for (int off = 8; off; off >>= 1) pr += __shfl_xor(pr, off);  // reduce over lr group
            if (lr == 0) pspart[((size_t)which * 16384 + row) * 16 + strip] = pr;
        }
    }
}

// ---------------- 3. masked softmax + weighted sum over compact rows
// block = (b, which, col-half); thread owns 2 cols; local base scan (wave 0)
__global__ __launch_bounds__(256) void pool2_kernel(const unsigned short* __restrict__ motion,
                                                    const unsigned short* __restrict__ appearance,
                                                    const float* __restrict__ pspart,
                                                    const int* __restrict__ lens,
                                                    const float* __restrict__ b_pool,
                                                    float* __restrict__ out) {
    __shared__ float sm[256];
    __shared__ float red[8];
    __shared__ int sbase;
    const int which = blockIdx.x & 1;
    const int half = (blockIdx.x >> 1) & 1;
    const int b = blockIdx.x >> 2;
    const int t = threadIdx.x, lane = t & 63, wv = t >> 6;
    if (t < 64) {                                  // local compaction-base scan (wave 0)
        const int L2 = lens[t];
        const int v0 = which ? L2 : L2 - 2;
        int vi = v0;
        #pragma unroll
        for (int off = 1; off < 64; off <<= 1) {
            const int tv = __shfl_up(vi, off);
            if (t >= off) vi += tv;
        }
        if (t == b) sbase = vi - v0;
    }
    const int valid = which ? lens[b] : lens[b] - 2;
    __syncthreads();
    const int base = sbase;
    const unsigned short* mat = (which ? appearance : motion) + (size_t)base * 1024;
    float v = NEGF;
    if (t < valid) {
        const float* pp = pspart + ((size_t)which * 16384 + base + t) * 16;
        float s = 0.f;
        #pragma unroll
        for (int j = 0; j < 16; ++j) s += pp[j];
        v = gelu_erf(s + b_pool[0]);
    }
    float mx = v;
    #pragma unroll
    for (int off = 32; off; off >>= 1) mx = fmaxf(mx, __shfl_xor(mx, off));
    if (lane == 0) red[wv] = mx;
    __syncthreads();
    mx = fmaxf(fmaxf(red[0], red[1]), fmaxf(red[2], red[3]));
    const float e = expf(v - mx);                 // masked rows -> exactly 0
    float s = e;
    #pragma unroll
    for (int off = 32; off; off >>= 1) s += __shfl_xor(s, off);
    if (lane == 0) red[4 + wv] = s;
    __syncthreads();
    s = red[4] + red[5] + red[6] + red[7];
    sm[t] = e / s;
    __syncthreads();
    const int col0 = half * 512 + t * 2;
    float a0 = 0.f, a1 = 0.f;
    for (int l = 0; l < valid; ++l) {             // rows >= valid have weight exactly 0
        const float al = sm[l];
        const unsigned int hv = *(const unsigned int*)(mat + (size_t)l * 1024 + col0);
        a0 += al * bf2f((unsigned short)(hv & 0xFFFF));
        a1 += al * bf2f((unsigned short)(hv >> 16));
    }
    float* o = out + (size_t)b * 2048 + which * 1024 + col0;
    o[0] = a0; o[1] = a1;
}

extern "C" void kernel_launch(void* const* d_in, const int* in_sizes, int n_in,
                              void* d_out, int out_size, void* d_ws, size_t ws_size,
                              hipStream_t stream) {
    const float* clip_ft   = (const float*)d_in[0];
    const int*   clip_lens = (const int*)d_in[1];
    const float* w_mot_wei = (const float*)d_in[2];
    const float* b_mot_wei = (const float*)d_in[3];
    const float* w_mot_fc  = (const float*)d_in[4];
    const float* b_mot_fc  = (const float*)d_in[5];
    const float* w_app_fc  = (const float*)d_in[6];
    const float* b_app_fc  = (const float*)d_in[7];
    const float* w_pool    = (const float*)d_in[8];
    const float* b_pool    = (const float*)d_in[9];
    float* out = (float*)d_out;

    char* ws = (char*)d_ws;
    size_t off = 0;
    auto carve = [&](size_t bytes) { void* p = ws + off; off += (bytes + 255) & ~(size_t)255; return p; };
    float*          pspart = (float*)carve((size_t)2 * 16384 * 16 * 4);
    unsigned short* wmotT  = (unsigned short*)carve((size_t)1024 * 2048 * 2);
    unsigned short* wappT  = (unsigned short*)carve((size_t)1024 * 2048 * 2);
    unsigned short* appb   = (unsigned short*)carve((size_t)64 * 256 * 2048 * 2);  // compact
    unsigned short* vidb   = (unsigned short*)carve((size_t)64 * 256 * 2048 * 2);  // compact
    unsigned short* motion = (unsigned short*)carve((size_t)64 * 256 * 1024 * 2);  // compact
    unsigned short* appear = (unsigned short*)carve((size_t)64 * 256 * 1024 * 2);  // compact
    (void)ws_size; (void)in_sizes; (void)n_in; (void)out_size;

    fused1_kernel<<<2560, 256, 0, stream>>>(w_mot_fc, w_app_fc, clip_ft, clip_lens,
                                            w_mot_wei, b_mot_wei, wmotT, wappT, appb, vidb);
    gemm3q_kernel<<<1024, 512, 0, stream>>>(vidb, appb, wmotT, wappT,
                                            b_mot_fc, b_app_fc, w_pool, clip_lens,
                                            motion, appear, pspart);
    pool2_kernel<<<256, 256, 0, stream>>>(motion, appear, pspart, clip_lens, b_pool, out);
}

// Round 17
// 154.574 us; speedup vs baseline: 1.9101x; 1.0033x over previous
//
#include <hip/hip_runtime.h>
#include <cstdint>

#define NEGF (-1e18f)
#define GK 2048   // GEMM K
#define GN 1024   // GEMM N

typedef __attribute__((ext_vector_type(8))) short short8;     // 8 bf16 (4 VGPRs) MFMA A/B frag
typedef __attribute__((ext_vector_type(4))) float f32x4;      // MFMA C/D frag
typedef __attribute__((ext_vector_type(4))) unsigned short us4;
typedef __attribute__((ext_vector_type(8))) unsigned short us8;

__device__ __forceinline__ unsigned short f2bf(float f) {
    unsigned int u = __float_as_uint(f);
    u += 0x7FFFu + ((u >> 16) & 1u);          // RNE
    return (unsigned short)(u >> 16);
}
__device__ __forceinline__ float bf2f(unsigned short h) {
    return __uint_as_float(((unsigned int)h) << 16);
}
__device__ __forceinline__ float gelu_erf(float x) {
    return 0.5f * x * (1.0f + erff(x * 0.70710678118654752f));
}
// tanh-form GELU: max |diff| vs erf-GELU < 1e-3 (small vs 2.1e-2 threshold)
__device__ __forceinline__ float gelu_fast(float x) {
    const float y = 1.5957691216057308f * (x + 0.044715f * x * x * x);
    const float t = 1.0f - 2.0f / (__expf(y) + 1.0f);
    return 0.5f * x * (1.0f + t);
}
__device__ __forceinline__ void async_copy16(const void* g, void* l) {
    __builtin_amdgcn_global_load_lds(
        (const __attribute__((address_space(1))) unsigned int*)g,
        (__attribute__((address_space(3))) unsigned int*)l,
        16, 0, 0);
}

// ---------------- 1. FUSED: weight transpose (blocks 0..2047) + prep (blocks 2048..2559)
__global__ __launch_bounds__(256) void fused1_kernel(const float* __restrict__ wmot,
                                                     const float* __restrict__ wapp,
                                                     const float* __restrict__ clip_ft,
                                                     const int* __restrict__ lens,
                                                     const float* __restrict__ w_mot_wei,
                                                     const float* __restrict__ bsc,
                                                     unsigned short* __restrict__ wmotT,
                                                     unsigned short* __restrict__ wappT,
                                                     unsigned short* __restrict__ app,   // compact
                                                     unsigned short* __restrict__ vid) { // compact
    if (blockIdx.x < 2048) {                       // ---- weight transpose + bf16 convert
        const int which = blockIdx.x >> 10;
        const float* w = which ? wapp : wmot;
        unsigned short* wT = which ? wappT : wmotT;
        const int idx = (blockIdx.x & 1023) * 256 + threadIdx.x;
        const int n = idx & 1023;
        const int k0 = (idx >> 10) << 3;
        us8 o;
        #pragma unroll
        for (int j = 0; j < 8; ++j) o[j] = f2bf(w[(size_t)(k0 + j) * 1024 + n]);
        *(us8*)(wT + (size_t)n * 2048 + k0) = o;
        return;
    }
    // ---- prep part
    __shared__ float sm2[2][4];
    __shared__ int sb2[2];
    const int bid = blockIdx.x - 2048;
    const int b = bid >> 3;
    const int c = bid & 7;
    const int len = lens[b];
    const int l0 = c * 32;
    if (l0 >= len) return;                         // block-uniform: nothing valid here
    const int t = threadIdx.x;
    if (t < 64) {                                  // local compaction-base scan (wave 0)
        const int L2 = lens[t];
        const int m0 = L2 - 2, a0 = L2;
        int mi = m0, ai = a0;
        #pragma unroll
        for (int off = 1; off < 64; off <<= 1) {
            const int tm = __shfl_up(mi, off);
            const int ta = __shfl_up(ai, off);
            if (t >= off) { mi += tm; ai += ta; }
        }
        if (t == b) { sb2[0] = mi - m0; sb2[1] = ai - a0; }
    }
    const int lane = t & 63, wv = t >> 6;
    const int d0 = t * 8;
    const float bias = bsc[0];
    const float* base = clip_ft + ((size_t)b * 256) * 2048 + d0;
    float wm[8];
    {
        f32x4 u = *(const f32x4*)(w_mot_wei + d0);
        f32x4 v = *(const f32x4*)(w_mot_wei + d0 + 4);
        #pragma unroll
        for (int j = 0; j < 4; ++j) { wm[j] = u[j]; wm[4 + j] = v[j]; }
    }
    __syncthreads();                               // publishes sb2
    const int bm = sb2[0], ba = sb2[1];
    float x0[8], x1[8], cur[8], nxt[8];
    {                                              // preload row l0 (live by construction)
        const f32x4* p = (const f32x4*)(base + (size_t)l0 * 2048);
        f32x4 u = p[0], v = p[1];
        #pragma unroll
        for (int j = 0; j < 4; ++j) { cur[j] = u[j]; cur[4 + j] = v[j]; }
    }
    float sc0 = NEGF, sc1 = NEGF, sc2 = NEGF;
    for (int i = 0; i < 34; ++i) {
        const int l = l0 + i;
        const bool live = (l < len);               // block-uniform
        const bool liveN = (i < 33) && (l + 1 < len);
        if (liveN) {                               // prefetch next row: flies under reduce+sync
            const f32x4* p = (const f32x4*)(base + (size_t)(l + 1) * 2048);
            f32x4 u = p[0], v = p[1];
            #pragma unroll
            for (int j = 0; j < 4; ++j) { nxt[j] = u[j]; nxt[4 + j] = v[j]; }
        }
        if (live) {
            if (i < 32) {                          // compact app write (valid rows only)
                us8 o;
                #pragma unroll
                for (int j = 0; j < 8; ++j) o[j] = f2bf(cur[j]);
                *(us8*)(app + ((size_t)(ba + l)) * 2048 + d0) = o;
            }
            float p8 = cur[0]*wm[0] + cur[1]*wm[1] + cur[2]*wm[2] + cur[3]*wm[3]
                     + cur[4]*wm[4] + cur[5]*wm[5] + cur[6]*wm[6] + cur[7]*wm[7];
            #pragma unroll
            for (int off = 32; off; off >>= 1) p8 += __shfl_xor(p8, off);
            if (lane == 0) sm2[i & 1][wv] = p8;
        }
        __syncthreads();                           // uniform; publishes sm2[i&1]
        sc2 = live ? (sm2[i & 1][0] + sm2[i & 1][1]) + (sm2[i & 1][2] + sm2[i & 1][3]) + bias
                   : NEGF;
        if (i >= 2) {
            const int lw = l - 2;
            if (lw < len - 2) {                    // valid motion rows only, compact position
                const float mx = fmaxf(sc0, fmaxf(sc1, sc2));
                const float e0 = expf(sc0 - mx), e1 = expf(sc1 - mx), e2 = expf(sc2 - mx);
                const float inv = 1.0f / (e0 + e1 + e2);
                const float a0 = e0 * inv, a1 = e1 * inv, a2 = e2 * inv;
                us8 o;
                #pragma unroll
                for (int j = 0; j < 8; ++j) o[j] = f2bf(a0 * x0[j] + a1 * x1[j] + a2 * cur[j]);
                *(us8*)(vid + ((size_t)(bm + lw)) * 2048 + d0) = o;
            }
        }
        #pragma unroll
        for (int j = 0; j < 8; ++j) { x0[j] = x1[j]; x1[j] = cur[j]; if (liveN) cur[j] = nxt[j]; }
        sc0 = sc1; sc1 = sc2;
    }
}

// ---------------- 2. fused dual bf16 MFMA GEMM over COMPACT rows — 128x128 tile, BK=32,
// 8 waves (2Mx4N, 64x32/wave), 3 LDS bufs (48KB) depth-2 counted-vmcnt, 3 blocks/CU.
// R17: tile halved (256->128 N) to fix the scheduling-quantization tail: ~1032 live
// blocks on 768 slots = 2 uniform start-waves (R16: 516 on 512 = 2 rounds, 2nd round
// only 4 blocks -> GEMM paid 2x for 0.8% overhang).
__global__ __launch_bounds__(512, 6) void gemm3q_kernel(
        const unsigned short* __restrict__ Avid, const unsigned short* __restrict__ Aapp,
        const unsigned short* __restrict__ Bmot, const unsigned short* __restrict__ Bapp,
        const float* __restrict__ bmot, const float* __restrict__ bapp,
        const float* __restrict__ w_pool, const int* __restrict__ lens,
        unsigned short* __restrict__ Cmot, unsigned short* __restrict__ Capp,
        float* __restrict__ pspart) {             // [2][16384][32] strip partials (compact rows)
    __shared__ __align__(16) unsigned short lds_[3 * 8192]; // 48KB: 3 x (A 8KB | B 8KB)
    __shared__ int stot;
    const int bid = blockIdx.x;                   // 2048 blocks
    const int virt = (bid & 7) * 256 + (bid >> 3);            // XCD-bijective (2048%8==0)
    const int which = virt >> 10;
    const int rem = virt & 1023;
    const int ntile = rem & 7;                    // ntile fastest: A-panel shared in-XCD
    const int mt_idx = rem >> 3;                  // 0..127
    const int mtile = (mt_idx & 31) * 4 + (mt_idx >> 5);      // stride-4: balance across XCDs
    const int row0 = mtile * 128, col0 = ntile * 128;
    if (threadIdx.x < 64) {                       // local total (wave 0)
        int v = lens[threadIdx.x] - (which ? 0 : 2);
        #pragma unroll
        for (int off = 32; off; off >>= 1) v += __shfl_xor(v, off);
        if (threadIdx.x == 0) stot = v;
    }
    __syncthreads();
    if (row0 >= stot) return;                     // beyond compacted rows: nothing to do
    const unsigned short* A  = which ? Aapp : Avid;
    const unsigned short* Bt = which ? Bapp : Bmot;
    const float* bias        = which ? bapp : bmot;
    unsigned short* C        = which ? Capp : Cmot;
    const int t = threadIdx.x, lane = t & 63, wave = t >> 6;
    const int wm = wave >> 2, wn = wave & 3;      // 2M x 4N waves, 64x32 each
    const int lr = lane & 15, sl = lane >> 4;     // frag row-in-16, k-slot 0..3

    // staging: thread t -> LDS[srow][t&3] linear; source k-slot pre-swizzled:
    // involution slot ^= (row>>1)&3 (conflicts=0)
    const int srow = t >> 2;                      // 0..127
    const int sk16 = (t & 3) ^ ((srow >> 1) & 3);
    const unsigned short* gA = A  + (size_t)(row0 + srow) * GK + sk16 * 8;
    const unsigned short* gB = Bt + (size_t)(col0 + srow) * GK + sk16 * 8;   // cols 0-127
    const int wbase = wave << 9;                  // 1KB per wave within a call

#define STAGE(d, kt) do { \
    async_copy16(gA + (kt) * 32, lds_ + (d) * 8192 +        wbase); \
    async_copy16(gB + (kt) * 32, lds_ + (d) * 8192 + 4096 + wbase); } while (0)

#define KSTEP(CUR) do { \
    const unsigned short* lb = lds_ + (CUR) * 8192; \
    short8 aF[4], bF[2]; \
    _Pragma("unroll") \
    for (int m = 0; m < 4; ++m) { \
        const int r = wm * 64 + m * 16 + lr; \
        aF[m] = *(const short8*)(lb + r * 32 + ((sl ^ ((r >> 1) & 3)) << 3)); \
    } \
    _Pragma("unroll") \
    for (int n = 0; n < 2; ++n) { \
        const int cc = wn * 32 + n * 16 + lr; \
        bF[n] = *(const short8*)(lb + 4096 + cc * 32 + ((sl ^ ((cc >> 1) & 3)) << 3)); \
    } \
    _Pragma("unroll") \
    for (int m = 0; m < 4; ++m) \
        _Pragma("unroll") \
        for (int n = 0; n < 2; ++n) \
            acc[m][n] = __builtin_amdgcn_mfma_f32_16x16x32_bf16(aF[m], bF[n], acc[m][n], 0, 0, 0); \
    } while (0)

    f32x4 acc[4][2] = {};
    STAGE(0, 0);
    STAGE(1, 1);

    int cur = 0, stg = 2;
    #pragma unroll 3
    for (int kt = 0; kt < 62; ++kt) {
        // stage(kt) retired; stage(kt+1)'s 2 calls stay in flight
        asm volatile("s_waitcnt vmcnt(2)" ::: "memory");
        __builtin_amdgcn_s_barrier();
        __builtin_amdgcn_sched_barrier(0);
        STAGE(stg, kt + 2);                        // full compute phase of flight time
        KSTEP(cur);
        cur = (cur == 2) ? 0 : cur + 1;
        stg = (stg == 2) ? 0 : stg + 1;
    }
    // kt = 62: outstanding = stage(62) 2 + stage(63) 2
    asm volatile("s_waitcnt vmcnt(2)" ::: "memory");
    __builtin_amdgcn_s_barrier();
    __builtin_amdgcn_sched_barrier(0);
    KSTEP(cur);
    cur = (cur == 2) ? 0 : cur + 1;
    // kt = 63: drain
    asm volatile("s_waitcnt vmcnt(0)" ::: "memory");
    __builtin_amdgcn_s_barrier();
    __builtin_amdgcn_sched_barrier(0);
    KSTEP(cur);
#undef STAGE
#undef KSTEP

    // epilogue: C/D layout col=lane&15, row=(lane>>4)*4+i (HW-verified m89/m91)
    // + pool-dot partials per 32-col strip (strip = ntile*4 + wn, 0..31)
    float wp[2], bz[2];
    #pragma unroll
    for (int n = 0; n < 2; ++n) {
        const int col = col0 + wn * 32 + n * 16 + lr;
        wp[n] = w_pool[col];
        bz[n] = bias[col];
    }
    const int strip = ntile * 4 + wn;
    #pragma unroll
    for (int m = 0; m < 4; ++m) {
        #pragma unroll
        for (int i = 0; i < 4; ++i) {
            const int row = row0 + wm * 64 + m * 16 + sl * 4 + i;   // compact row
            float pr = 0.f;
            #pragma unroll
            for (int n = 0; n < 2; ++n) {
                const int col = col0 + wn * 32 + n * 16 + lr;
                const float g = gelu_fast(acc[m][n][i] + bz[n]);
                pr += g * wp[n];
                C[(size_t)row * GN + col] = f2bf(g);
            }
            #pragma unroll
            for (int off = 8; off; off >>= 1) pr += __shfl_xor(pr, off);  // reduce over lr group
            if (lr == 0) pspart[((size_t)which * 16384 + row) * 32 + strip] = pr;
        }
    }
}

// ---------------- 3. masked softmax + weighted sum over compact rows
// block = (b, which, col-half); thread owns 2 cols; local base scan (wave 0)
__global__ __launch_bounds__(256) void pool2_kernel(const unsigned short* __restrict__ motion,
                                                    const unsigned short* __restrict__ appearance,
                                                    const float* __restrict__ pspart,
                                                    const int* __restrict__ lens,
                                                    const float* __restrict__ b_pool,
                                                    float* __restrict__ out) {
    __shared__ float sm[256];
    __shared__ float red[8];
    __shared__ int sbase;
    const int which = blockIdx.x & 1;
    const int half = (blockIdx.x >> 1) & 1;
    const int b = blockIdx.x >> 2;
    const int t = threadIdx.x, lane = t & 63, wv = t >> 6;
    if (t < 64) {                                  // local compaction-base scan (wave 0)
        const int L2 = lens[t];
        const int v0 = which ? L2 : L2 - 2;
        int vi = v0;
        #pragma unroll
        for (int off = 1; off < 64; off <<= 1) {
            const int tv = __shfl_up(vi, off);
            if (t >= off) vi += tv;
        }
        if (t == b) sbase = vi - v0;
    }
    const int valid = which ? lens[b] : lens[b] - 2;
    __syncthreads();
    const int base = sbase;
    const unsigned short* mat = (which ? appearance : motion) + (size_t)base * 1024;
    float v = NEGF;
    if (t < valid) {
        const float* pp = pspart + ((size_t)which * 16384 + base + t) * 32;
        float s = 0.f;
        #pragma unroll
        for (int j = 0; j < 32; ++j) s += pp[j];
        v = gelu_erf(s + b_pool[0]);
    }
    float mx = v;
    #pragma unroll
    for (int off = 32; off; off >>= 1) mx = fmaxf(mx, __shfl_xor(mx, off));
    if (lane == 0) red[wv] = mx;
    __syncthreads();
    mx = fmaxf(fmaxf(red[0], red[1]), fmaxf(red[2], red[3]));
    const float e = expf(v - mx);                 // masked rows -> exactly 0
    float s = e;
    #pragma unroll
    for (int off = 32; off; off >>= 1) s += __shfl_xor(s, off);
    if (lane == 0) red[4 + wv] = s;
    __syncthreads();
    s = red[4] + red[5] + red[6] + red[7];
    sm[t] = e / s;
    __syncthreads();
    const int col0 = half * 512 + t * 2;
    float a0 = 0.f, a1 = 0.f;
    for (int l = 0; l < valid; ++l) {             // rows >= valid have weight exactly 0
        const float al = sm[l];
        const unsigned int hv = *(const unsigned int*)(mat + (size_t)l * 1024 + col0);
        a0 += al * bf2f((unsigned short)(hv & 0xFFFF));
        a1 += al * bf2f((unsigned short)(hv >> 16));
    }
    float* o = out + (size_t)b * 2048 + which * 1024 + col0;
    o[0] = a0; o[1] = a1;
}

extern "C" void kernel_launch(void* const* d_in, const int* in_sizes, int n_in,
                              void* d_out, int out_size, void* d_ws, size_t ws_size,
                              hipStream_t stream) {
    const float* clip_ft   = (const float*)d_in[0];
    const int*   clip_lens = (const int*)d_in[1];
    const float* w_mot_wei = (const float*)d_in[2];
    const float* b_mot_wei = (const float*)d_in[3];
    const float* w_mot_fc  = (const float*)d_in[4];
    const float* b_mot_fc  = (const float*)d_in[5];
    const float* w_app_fc  = (const float*)d_in[6];
    const float* b_app_fc  = (const float*)d_in[7];
    const float* w_pool    = (const float*)d_in[8];
    const float* b_pool    = (const float*)d_in[9];
    float* out = (float*)d_out;

    char* ws = (char*)d_ws;
    size_t off = 0;
    auto carve = [&](size_t bytes) { void* p = ws + off; off += (bytes + 255) & ~(size_t)255; return p; };
    float*          pspart = (float*)carve((size_t)2 * 16384 * 32 * 4);
    unsigned short* wmotT  = (unsigned short*)carve((size_t)1024 * 2048 * 2);
    unsigned short* wappT  = (unsigned short*)carve((size_t)1024 * 2048 * 2);
    unsigned short* appb   = (unsigned short*)carve((size_t)64 * 256 * 2048 * 2);  // compact
    unsigned short* vidb   = (unsigned short*)carve((size_t)64 * 256 * 2048 * 2);  // compact
    unsigned short* motion = (unsigned short*)carve((size_t)64 * 256 * 1024 * 2);  // compact
    unsigned short* appear = (unsigned short*)carve((size_t)64 * 256 * 1024 * 2);  // compact
    (void)ws_size; (void)in_sizes; (void)n_in; (void)out_size;

    fused1_kernel<<<2560, 256, 0, stream>>>(w_mot_fc, w_app_fc, clip_ft, clip_lens,
                                            w_mot_wei, b_mot_wei, wmotT, wappT, appb, vidb);
    gemm3q_kernel<<<2048, 512, 0, stream>>>(vidb, appb, wmotT, wappT,
                                            b_mot_fc, b_app_fc, w_pool, clip_lens,
                                            motion, appear, pspart);
    pool2_kernel<<<256, 256, 0, stream>>>(motion, appear, pspart, clip_lens, b_pool, out);
}